// Round 6
// baseline (2130.905 us; speedup 1.0000x reference)
//
#include <hip/hip_runtime.h>
#include <hip/hip_bf16.h>
#include <cstddef>
#include <cstdint>

#define DIV_UP(a, b) (((a) + (b) - 1) / (b))

typedef __attribute__((ext_vector_type(8))) short bf16x8v;
typedef __attribute__((ext_vector_type(4))) float f32x4v;

__device__ __forceinline__ unsigned short bf16_rn(float v) {
    unsigned int u = __float_as_uint(v);
    unsigned int r = (u + 0x7FFFu + ((u >> 16) & 1u)) >> 16;
    return (unsigned short)r;
}
__device__ __forceinline__ float bf16_f(unsigned short h) {
    return __uint_as_float(((unsigned int)h) << 16);
}
__device__ __forceinline__ void f2hl(float v, unsigned short& hi, unsigned short& lo) {
    hi = bf16_rn(v);
    float r = v - bf16_f(hi);
    lo = bf16_rn(r);
}
__device__ __forceinline__ int xcd_swz(int orig, int nwg) {
    int q = nwg >> 3, r = nwg & 7;
    int xcd = orig & 7, idx = orig >> 3;
    return (xcd < r ? xcd * (q + 1) : r * (q + 1) + (xcd - r) * q) + idx;
}

// ---------------- transpose (C,H,W) f32 -> (H*W, C) bf16 hi/lo --------------
__global__ void transpose_hl(const float* __restrict__ in, unsigned short* __restrict__ ohi,
                             unsigned short* __restrict__ olo, int C, int HW) {
    int idx = blockIdx.x * 256 + threadIdx.x;
    if (idx >= C * HW) return;
    int c = idx % C;
    int p = idx / C;
    float v = in[(size_t)c * HW + p];
    unsigned short hi, lo;
    f2hl(v, hi, lo);
    ohi[(size_t)p * C + c] = hi;
    olo[(size_t)p * C + c] = lo;
}

// ---------------- single fused weight-pack kernel ---------------------------
struct PackArgs {
    const float* Win0[3]; const float* Win1[3];   // [1408|1283][128]
    const float* W0L[3];  const float* W1L[3];    // [12][128][128]
    unsigned short *BtLhi[3], *BtLlo[3];          // [12][128][256]
    unsigned short *BtShi[2], *BtSlo[2];          // stages 1,2: [256][128]
    unsigned short *Bgh[3], *Bgl[3];              // [768][C] C=256,512,512
};

__global__ void pack_all(PackArgs p) {
    const int LAY1 = 12 * 128 * 256;           // 393216 per stage
    const int LAYT = 3 * LAY1;                 // 1179648
    const int SH1 = 256 * 128;                 // 32768 per stage
    const int SHT = 2 * SH1;
    const int GB0 = 768 * 256, GB1 = 768 * 512;
    int idx = blockIdx.x * 256 + threadIdx.x;
    float v;
    unsigned short* dh;
    unsigned short* dl;
    size_t o;
    if (idx < LAYT) {
        int st = idx / LAY1, r = idx % LAY1;
        int l = r >> 15, rr = r & 32767;
        int n = rr >> 8, k = rr & 255;
        v = (k < 128) ? p.W0L[st][(size_t)l * 16384 + k * 128 + n]
                      : p.W1L[st][(size_t)l * 16384 + (k - 128) * 128 + n];
        dh = p.BtLhi[st]; dl = p.BtLlo[st]; o = r;
    } else if (idx < LAYT + SHT) {
        int q = idx - LAYT;
        int st = q / SH1, rr = q % SH1;
        int n = rr >> 7, k = rr & 127;
        const float* w0 = p.Win0[st + 1];
        const float* w1 = p.Win1[st + 1];
        v = (n < 128) ? w0[(size_t)(1280 + k) * 128 + n]
                      : w1[(size_t)(1280 + k) * 128 + (n - 128)];
        dh = p.BtShi[st]; dl = p.BtSlo[st]; o = rr;
    } else {
        int q = idx - LAYT - SHT;
        int m, C, base;
        if (q < GB0) { m = 0; C = 256; base = 0; }
        else if (q < GB0 + GB1) { m = 1; C = 512; base = 256; q -= GB0; }
        else if (q < GB0 + 2 * GB1) { m = 2; C = 512; base = 768; q -= GB0 + GB1; }
        else return;
        int n = q / C, k = q % C;
        int s = n >> 8, j = n & 255;
        v = (j < 128) ? p.Win0[s][(size_t)(base + k) * 128 + j]
                      : p.Win1[s][(size_t)(base + k) * 128 + (j - 128)];
        dh = p.Bgh[m]; dl = p.Bgl[m]; o = q;
    }
    unsigned short hi, lo;
    f2hl(v, hi, lo);
    dh[o] = hi;
    dl[o] = lo;
}

// -------- per-vertex projection/bilerp descriptors + fixed-degree adj -------
__global__ void desc_adj_kernel(const float* __restrict__ verts,
                                const float* __restrict__ cam_c, const float* __restrict__ cam_f,
                                const int* __restrict__ imgsz, int V,
                                const int* __restrict__ src, const int* __restrict__ dst, int E,
                                int* __restrict__ sampi, float* __restrict__ sampw,
                                int* __restrict__ adj8) {
    int v = blockIdx.x * 256 + threadIdx.x;
    if (v >= V) return;
    float X = verts[3 * v + 0], Yy = verts[3 * v + 1], Z = verts[3 * v + 2];
    float cx = cam_c[0], cy = cam_c[1], fx = cam_f[0], fy = cam_f[1];
    const float tz = 0.8f;
    float pz = Z + tz;
    float px = (fx * X + cx * Z + tz * cx) / pz;
    float py = (fy * Yy + cy * Z + tz * cy) / pz;
    float is = (float)imgsz[0];
    const int Ss[3] = {56, 28, 14};
#pragma unroll
    for (int m = 0; m < 3; ++m) {
        int S = Ss[m];
        float dim = (float)S;
        float x = px * dim / is;
        float y = py * dim / is;
        float x1 = floorf(x), y1 = floorf(y);
        float x2 = x1 + 1.0f, y2 = y1 + 1.0f;
        float smax = (float)(S - 1);
        int xi1 = (int)fminf(fmaxf(x1, 0.0f), smax);
        int xi2 = (int)fminf(fmaxf(x2, 0.0f), smax);
        int yi1 = (int)fminf(fmaxf(y1, 0.0f), smax);
        int yi2 = (int)fminf(fmaxf(y2, 0.0f), smax);
        int b = v * 12 + m * 4;
        sampi[b + 0] = xi1 * S + yi1;
        sampi[b + 1] = xi1 * S + yi2;
        sampi[b + 2] = xi2 * S + yi1;
        sampi[b + 3] = xi2 * S + yi2;
        sampw[b + 0] = (x2 - x) * (y2 - y);
        sampw[b + 1] = (x2 - x) * (y - y1);
        sampw[b + 2] = (x - x1) * (y2 - y);
        sampw[b + 3] = (x - x1) * (y - y1);
    }
    // fixed-degree adjacency via two binary searches on sorted src
    int lo = 0, hi = E;
    while (lo < hi) { int m = (lo + hi) >> 1; if (src[m] < v) lo = m + 1; else hi = m; }
    int e0 = lo;
    hi = E;
    while (lo < hi) { int m = (lo + hi) >> 1; if (src[m] < v + 1) lo = m + 1; else hi = m; }
    int e1 = lo;
    int* ap = adj8 + (size_t)v * 8;
#pragma unroll
    for (int i = 0; i < 8; ++i) {
        int e = e0 + i;
        ap[i] = (e < e1) ? dst[e] : -1;
    }
}

// ---------------- MFMA bf16x3 GEMM (G precompute + shape GEMM) --------------
// EPI 2: G precompute scatter-store; EPI 3: plain store Y[row*256+col].
struct MArgs {
    const unsigned short *Ahi, *Alo; int lda;
    const unsigned short *Bhi, *Blo; int K;  // Bt row-major [N][K]
    float* Y;
    int sstr;
    int V;
};

template <int EPI>
__global__ __launch_bounds__(256) void mgemm(MArgs g) {
    __shared__ unsigned short As_hi[64][40], As_lo[64][40];
    __shared__ unsigned short Bs_hi[128][40], Bs_lo[128][40];
    int tid = threadIdx.x;
    int row0 = blockIdx.y * 64;
    int col0 = blockIdx.x * 128;
    int l = tid & 63, wid = tid >> 6;
    int wr = wid & 1, wc = wid >> 1;
    int lw = l & 15, gg = l >> 4;
    f32x4v acc[2][4];
#pragma unroll
    for (int i = 0; i < 2; ++i)
#pragma unroll
        for (int j = 0; j < 4; ++j) acc[i][j] = (f32x4v){0.f, 0.f, 0.f, 0.f};

    int arow = tid >> 2, akoff = (tid & 3) * 8;
    for (int k0 = 0; k0 < g.K; k0 += 32) {
        __syncthreads();
        {
            int grow = row0 + arow;
            uint4 zh = make_uint4(0, 0, 0, 0), zl = make_uint4(0, 0, 0, 0);
            if (grow < g.V) {
                zh = *(const uint4*)(g.Ahi + (size_t)grow * g.lda + k0 + akoff);
                zl = *(const uint4*)(g.Alo + (size_t)grow * g.lda + k0 + akoff);
            }
            *(uint4*)&As_hi[arow][akoff] = zh;
            *(uint4*)&As_lo[arow][akoff] = zl;
        }
#pragma unroll
        for (int it = 0; it < 2; ++it) {
            int q = tid + it * 256;
            int n = q >> 2, koff = (q & 3) * 8;
            *(uint4*)&Bs_hi[n][koff] = *(const uint4*)(g.Bhi + (size_t)(col0 + n) * g.K + k0 + koff);
            *(uint4*)&Bs_lo[n][koff] = *(const uint4*)(g.Blo + (size_t)(col0 + n) * g.K + k0 + koff);
        }
        __syncthreads();
        bf16x8v ah[2], al[2], bh[4], bl[4];
#pragma unroll
        for (int mt = 0; mt < 2; ++mt) {
            int r = wr * 32 + mt * 16 + lw;
            ah[mt] = *(const bf16x8v*)&As_hi[r][gg * 8];
            al[mt] = *(const bf16x8v*)&As_lo[r][gg * 8];
        }
#pragma unroll
        for (int nt = 0; nt < 4; ++nt) {
            int c = wc * 64 + nt * 16 + lw;
            bh[nt] = *(const bf16x8v*)&Bs_hi[c][gg * 8];
            bl[nt] = *(const bf16x8v*)&Bs_lo[c][gg * 8];
        }
#pragma unroll
        for (int mt = 0; mt < 2; ++mt)
#pragma unroll
            for (int nt = 0; nt < 4; ++nt) {
                acc[mt][nt] = __builtin_amdgcn_mfma_f32_16x16x32_bf16(ah[mt], bh[nt], acc[mt][nt], 0, 0, 0);
                acc[mt][nt] = __builtin_amdgcn_mfma_f32_16x16x32_bf16(ah[mt], bl[nt], acc[mt][nt], 0, 0, 0);
                acc[mt][nt] = __builtin_amdgcn_mfma_f32_16x16x32_bf16(al[mt], bh[nt], acc[mt][nt], 0, 0, 0);
            }
    }
#pragma unroll
    for (int mt = 0; mt < 2; ++mt)
#pragma unroll
        for (int nt = 0; nt < 4; ++nt) {
            int colg = wc * 64 + nt * 16 + lw;
#pragma unroll
            for (int r = 0; r < 4; ++r) {
                int rowg = row0 + wr * 32 + mt * 16 + gg * 4 + r;
                if (rowg >= g.V) continue;
                float v = acc[mt][nt][r];
                if (EPI == 3) {
                    g.Y[(size_t)rowg * 256 + col0 + colg] = v;
                } else {
                    int cg = col0 + colg;
                    g.Y[(size_t)(cg >> 8) * g.sstr + (size_t)rowg * 256 + (cg & 255)] = v;
                }
            }
        }
}

// ---------------- input perceptual gather (float4, 64 thr/vertex) -----------
__global__ void gather_kernel(const float* __restrict__ G, int sstr,
                              const int* __restrict__ sampi, const float* __restrict__ sampw,
                              float* __restrict__ Yb, int V, int stage,
                              const float* __restrict__ Win0, const float* __restrict__ Win1,
                              const float* __restrict__ shape) {
    int v = xcd_swz(blockIdx.x, gridDim.x) * 4 + (threadIdx.x >> 6);
    if (v >= V) return;
    int j = (threadIdx.x & 63) * 4;
    const float* Gs = G + (size_t)stage * sstr;
    int b = v * 12;
    float4 acc;
    if (stage == 0) acc = make_float4(0.f, 0.f, 0.f, 0.f);
    else acc = *(const float4*)(Yb + (size_t)v * 256 + j);
#pragma unroll
    for (int s = 0; s < 4; ++s) {
        float w = sampw[b + s];
        float4 f = *(const float4*)(Gs + (size_t)sampi[b + s] * 256 + j);
        acc.x += w * f.x; acc.y += w * f.y; acc.z += w * f.z; acc.w += w * f.w;
    }
#pragma unroll
    for (int s = 0; s < 4; ++s) {
        float w = sampw[b + 4 + s];
        float4 f = *(const float4*)(Gs + (size_t)(3136 + sampi[b + 4 + s]) * 256 + j);
        acc.x += w * f.x; acc.y += w * f.y; acc.z += w * f.z; acc.w += w * f.w;
    }
#pragma unroll
    for (int s = 0; s < 4; ++s) {
        float w = sampw[b + 8 + s];
        float4 f = *(const float4*)(Gs + (size_t)(3920 + sampi[b + 8 + s]) * 256 + j);
        acc.x += w * f.x; acc.y += w * f.y; acc.z += w * f.z; acc.w += w * f.w;
    }
    if (stage == 0) {
#pragma unroll
        for (int k = 0; k < 3; ++k) {
            float w = shape[v * 3 + k];
            const float* wr = (j < 128) ? Win0 + (size_t)(1280 + k) * 128 + j
                                        : Win1 + (size_t)(1280 + k) * 128 + (j - 128);
            float4 wv = *(const float4*)wr;
            acc.x += w * wv.x; acc.y += w * wv.y; acc.z += w * wv.z; acc.w += w * wv.w;
        }
    }
    *(float4*)(Yb + (size_t)v * 256 + j) = acc;
}

// ---------------- input-layer combine (float4, 32 thr/vertex) ---------------
__global__ __launch_bounds__(256) void combine_in(
    const float* __restrict__ Y, const float* __restrict__ bias,
    const int* __restrict__ adj8,
    float* __restrict__ hout, int V) {
    int v = xcd_swz(blockIdx.x, gridDim.x) * 8 + (threadIdx.x >> 5);
    if (v >= V) return;
    int d = (threadIdx.x & 31) * 4;
    float4 val = *(const float4*)(Y + (size_t)v * 256 + d);
    float4 b4 = *(const float4*)(bias + d);
    val.x += b4.x; val.y += b4.y; val.z += b4.z; val.w += b4.w;
    const int* ap = adj8 + (size_t)v * 8;
    int n[6];
#pragma unroll
    for (int i = 0; i < 6; ++i) n[i] = ap[i];
#pragma unroll
    for (int i = 0; i < 6; ++i) {
        if (n[i] >= 0) {
            float4 f = *(const float4*)(Y + (size_t)n[i] * 256 + 128 + d);
            val.x += f.x; val.y += f.y; val.z += f.z; val.w += f.w;
        }
    }
    val.x = fmaxf(val.x, 0.f); val.y = fmaxf(val.y, 0.f);
    val.z = fmaxf(val.z, 0.f); val.w = fmaxf(val.w, 0.f);
    *(float4*)(hout + (size_t)v * 128 + d) = val;
}

// ---------------- fused resnet layer: NO LDS, NO BARRIERS -------------------
// Wave = 16 rows. A-fragments loaded global->reg directly (lane l: row l&15,
// k-slice (l>>4)*8). Agg half summed in registers from <=6 neighbor rows.
// B-fragments from L2-resident weight table (lane l: col nt*16+(l&15)).
struct LArgs {
    const float* h;                                   // [V][128] f32
    const unsigned short *Bhi, *Blo;                  // [128][256]
    const int* adj8;
    const float* bias;
    float* hnext;
    int V;
};

__global__ __launch_bounds__(256) void lay_kernel(LArgs g) {
    int tid = threadIdx.x;
    int wid = tid >> 6, l = tid & 63;
    int rowbase = (xcd_swz(blockIdx.x, gridDim.x) * 4 + wid) * 16;
    int lrow = l & 15, lks = l >> 4;
    int grow = rowbase + lrow;
    bool act = grow < g.V;

    f32x4v acc[8];
#pragma unroll
    for (int nt = 0; nt < 8; ++nt) acc[nt] = (f32x4v){0.f, 0.f, 0.f, 0.f};

    const float* hrow = g.h + (size_t)grow * 128;
    int n[6];
    if (act) {
        const int* ap = g.adj8 + (size_t)grow * 8;
#pragma unroll
        for (int i = 0; i < 6; ++i) n[i] = ap[i];
    } else {
#pragma unroll
        for (int i = 0; i < 6; ++i) n[i] = -1;
    }

    const unsigned short* Bh = g.Bhi + lrow * 256;
    const unsigned short* Bl = g.Blo + lrow * 256;

    auto do_step = [&](int kb, const float* a) {
        unsigned short hh[8], ll[8];
#pragma unroll
        for (int i = 0; i < 8; ++i) f2hl(a[i], hh[i], ll[i]);
        bf16x8v ah = *(const bf16x8v*)hh;
        bf16x8v al = *(const bf16x8v*)ll;
#pragma unroll
        for (int nt = 0; nt < 8; ++nt) {
            bf16x8v bh = *(const bf16x8v*)(Bh + nt * 4096 + kb);
            bf16x8v bl = *(const bf16x8v*)(Bl + nt * 4096 + kb);
            acc[nt] = __builtin_amdgcn_mfma_f32_16x16x32_bf16(ah, bh, acc[nt], 0, 0, 0);
            acc[nt] = __builtin_amdgcn_mfma_f32_16x16x32_bf16(ah, bl, acc[nt], 0, 0, 0);
            acc[nt] = __builtin_amdgcn_mfma_f32_16x16x32_bf16(al, bh, acc[nt], 0, 0, 0);
        }
    };

    // ---- own half: k-global 0..127 ----
#pragma unroll
    for (int ks = 0; ks < 4; ++ks) {
        int kb = ks * 32 + lks * 8;
        float a[8];
        if (act) {
            float4 f0 = *(const float4*)(hrow + kb);
            float4 f1 = *(const float4*)(hrow + kb + 4);
            a[0] = f0.x; a[1] = f0.y; a[2] = f0.z; a[3] = f0.w;
            a[4] = f1.x; a[5] = f1.y; a[6] = f1.z; a[7] = f1.w;
        } else {
#pragma unroll
            for (int i = 0; i < 8; ++i) a[i] = 0.f;
        }
        do_step(kb, a);
    }

    // ---- agg half: k-global 128..255, sum <=6 neighbor rows in regs ----
#pragma unroll
    for (int ks = 0; ks < 4; ++ks) {
        int ko = ks * 32 + lks * 8;
        float a[8];
#pragma unroll
        for (int i = 0; i < 8; ++i) a[i] = 0.f;
#pragma unroll
        for (int i = 0; i < 6; ++i) {
            if (n[i] >= 0) {
                const float* hp = g.h + (size_t)n[i] * 128 + ko;
                float4 f0 = *(const float4*)hp;
                float4 f1 = *(const float4*)(hp + 4);
                a[0] += f0.x; a[1] += f0.y; a[2] += f0.z; a[3] += f0.w;
                a[4] += f1.x; a[5] += f1.y; a[6] += f1.z; a[7] += f1.w;
            }
        }
        do_step(128 + ko, a);
    }

    // ---- epilogue: hnext = relu(acc + bias) + h ----
#pragma unroll
    for (int nt = 0; nt < 8; ++nt) {
        int colg = nt * 16 + lrow;
        float bv = g.bias[colg];
#pragma unroll
        for (int r = 0; r < 4; ++r) {
            int rowg = rowbase + lks * 4 + r;
            if (rowg < g.V) {
                float v = acc[nt][r] + bv;
                v = fmaxf(v, 0.0f);
                v += g.h[(size_t)rowg * 128 + colg];
                g.hnext[(size_t)rowg * 128 + colg] = v;
            }
        }
    }
}

// ---------------- coord head ------------------------------------------------
__global__ void coordgemm_kernel(const float* __restrict__ h,
                                 const float* __restrict__ Wc0, const float* __restrict__ Wc1,
                                 int V, float* __restrict__ Yc) {
    int idx = blockIdx.x * 256 + threadIdx.x;
    if (idx >= V * 6) return;
    int v = idx / 6, j = idx % 6;
    const float* W = (j < 3) ? Wc0 : Wc1;
    int jj = (j < 3) ? j : j - 3;
    const float* hp = h + (size_t)v * 128;
    float acc = 0.0f;
#pragma unroll
    for (int k = 0; k < 32; ++k) {
        float4 f = *(const float4*)(hp + k * 4);
        acc += f.x * W[(k * 4 + 0) * 3 + jj];
        acc += f.y * W[(k * 4 + 1) * 3 + jj];
        acc += f.z * W[(k * 4 + 2) * 3 + jj];
        acc += f.w * W[(k * 4 + 3) * 3 + jj];
    }
    Yc[idx] = acc;
}

__global__ void coordcombine_kernel(const float* __restrict__ Yc, const float* __restrict__ bc,
                                    const int* __restrict__ adj8,
                                    int V, float* __restrict__ out) {
    int idx = blockIdx.x * 256 + threadIdx.x;
    if (idx >= V * 3) return;
    int v = idx / 3, j = idx % 3;
    float val = Yc[(size_t)v * 6 + j] + bc[j];
    const int* ap = adj8 + (size_t)v * 8;
    int n[6];
#pragma unroll
    for (int i = 0; i < 6; ++i) n[i] = ap[i];
#pragma unroll
    for (int i = 0; i < 6; ++i)
        if (n[i] >= 0) val += Yc[(size_t)n[i] * 6 + 3 + j];
    out[(size_t)v * 3 + j] = val;
}

// ---------------- unpool: verts midpoints + featpack hi/lo ------------------
__global__ void unpool_kernel(float* __restrict__ verts, const float* __restrict__ h,
                              const int* __restrict__ mid, int V, int Nm,
                              unsigned short* __restrict__ fphi, unsigned short* __restrict__ fplo) {
    int r = blockIdx.x;
    int t = threadIdx.x;  // 128
    if (r < V) {
        float v = h[(size_t)r * 128 + t];
        unsigned short hi, lo;
        f2hl(v, hi, lo);
        fphi[(size_t)r * 128 + t] = hi;
        fplo[(size_t)r * 128 + t] = lo;
    } else {
        int i = r - V;
        int a = mid[2 * i], b = mid[2 * i + 1];
        float v = 0.5f * (h[(size_t)a * 128 + t] + h[(size_t)b * 128 + t]);
        unsigned short hi, lo;
        f2hl(v, hi, lo);
        fphi[(size_t)r * 128 + t] = hi;
        fplo[(size_t)r * 128 + t] = lo;
        if (t < 3)
            verts[(size_t)r * 3 + t] = 0.5f * (verts[(size_t)a * 3 + t] + verts[(size_t)b * 3 + t]);
    }
}

// ---------------------------------------------------------------------------
extern "C" void kernel_launch(void* const* d_in, const int* in_sizes, int n_in,
                              void* d_out, int out_size, void* d_ws, size_t ws_size,
                              hipStream_t stream) {
    const float* f3 = (const float*)d_in[0];
    const float* f4 = (const float*)d_in[1];
    const float* f5 = (const float*)d_in[2];
    const float* verts0 = (const float*)d_in[3];
    const float* cam_c = (const float*)d_in[4];
    const float* cam_f = (const float*)d_in[5];
    const int* imgsz = (const int*)d_in[38];

    int V0 = in_sizes[3] / 3;
    int E[3] = {in_sizes[33] / 2, in_sizes[34] / 2, in_sizes[35] / 2};
    int Nm0 = in_sizes[36] / 2, Nm1 = in_sizes[37] / 2;
    int V1 = V0 + Nm0, V2 = V1 + Nm1;
    int Vs[3] = {V0, V1, V2};
    const int NPIXT = 3136 + 784 + 196;  // 4116
    const int GS = NPIXT * 256;          // per-stage G stride (floats)

    // ---- workspace (byte allocator, 256B aligned) ----
    char* wsp = (char*)d_ws;
    auto alloc = [&](size_t bytes) -> void* {
        void* p = (void*)wsp;
        wsp += (bytes + 255) & ~(size_t)255;
        return p;
    };
    unsigned short* ft0h = (unsigned short*)alloc((size_t)3136 * 256 * 2);
    unsigned short* ft0l = (unsigned short*)alloc((size_t)3136 * 256 * 2);
    unsigned short* ft1h = (unsigned short*)alloc((size_t)784 * 512 * 2);
    unsigned short* ft1l = (unsigned short*)alloc((size_t)784 * 512 * 2);
    unsigned short* ft2h = (unsigned short*)alloc((size_t)196 * 512 * 2);
    unsigned short* ft2l = (unsigned short*)alloc((size_t)196 * 512 * 2);
    unsigned short* Bg0h = (unsigned short*)alloc((size_t)768 * 256 * 2);
    unsigned short* Bg0l = (unsigned short*)alloc((size_t)768 * 256 * 2);
    unsigned short* Bg1h = (unsigned short*)alloc((size_t)768 * 512 * 2);
    unsigned short* Bg1l = (unsigned short*)alloc((size_t)768 * 512 * 2);
    unsigned short* Bg2h = (unsigned short*)alloc((size_t)768 * 512 * 2);
    unsigned short* Bg2l = (unsigned short*)alloc((size_t)768 * 512 * 2);
    float* Gbuf = (float*)alloc((size_t)3 * GS * 4);
    unsigned short* BtLhi[3];
    unsigned short* BtLlo[3];
    for (int s = 0; s < 3; ++s) {
        BtLhi[s] = (unsigned short*)alloc((size_t)12 * 128 * 256 * 2);
        BtLlo[s] = (unsigned short*)alloc((size_t)12 * 128 * 256 * 2);
    }
    unsigned short* BtShi[2];
    unsigned short* BtSlo[2];
    for (int s = 0; s < 2; ++s) {
        BtShi[s] = (unsigned short*)alloc((size_t)256 * 128 * 2);
        BtSlo[s] = (unsigned short*)alloc((size_t)256 * 128 * 2);
    }
    float* Ybuf = (float*)alloc((size_t)V2 * 256 * 4);
    float* hA = (float*)alloc((size_t)V2 * 128 * 4);
    float* hB = (float*)alloc((size_t)V2 * 128 * 4);
    unsigned short* FPhi = (unsigned short*)alloc((size_t)V2 * 128 * 2);
    unsigned short* FPlo = (unsigned short*)alloc((size_t)V2 * 128 * 2);
    float* vertsbuf = (float*)alloc((size_t)V2 * 3 * 4);
    float* Yc = (float*)alloc((size_t)V2 * 6 * 4);
    int* sampi = (int*)alloc((size_t)V2 * 12 * 4);
    float* sampw = (float*)alloc((size_t)V2 * 12 * 4);
    int* adj8 = (int*)alloc((size_t)V2 * 8 * 4);

    // ---- feature map transpose + hi/lo split ----
    transpose_hl<<<DIV_UP(256 * 56 * 56, 256), 256, 0, stream>>>(f3, ft0h, ft0l, 256, 56 * 56);
    transpose_hl<<<DIV_UP(512 * 28 * 28, 256), 256, 0, stream>>>(f4, ft1h, ft1l, 512, 28 * 28);
    transpose_hl<<<DIV_UP(512 * 14 * 14, 256), 256, 0, stream>>>(f5, ft2h, ft2l, 512, 14 * 14);

    // ---- single fused weight pack ----
    {
        PackArgs p;
        for (int s = 0; s < 3; ++s) {
            p.Win0[s] = (const float*)d_in[6 + s * 9 + 0];
            p.Win1[s] = (const float*)d_in[6 + s * 9 + 1];
            p.W0L[s] = (const float*)d_in[6 + s * 9 + 3];
            p.W1L[s] = (const float*)d_in[6 + s * 9 + 4];
            p.BtLhi[s] = BtLhi[s]; p.BtLlo[s] = BtLlo[s];
        }
        p.BtShi[0] = BtShi[0]; p.BtSlo[0] = BtSlo[0];
        p.BtShi[1] = BtShi[1]; p.BtSlo[1] = BtSlo[1];
        p.Bgh[0] = Bg0h; p.Bgl[0] = Bg0l;
        p.Bgh[1] = Bg1h; p.Bgl[1] = Bg1l;
        p.Bgh[2] = Bg2h; p.Bgl[2] = Bg2l;
        int total = 3 * 12 * 128 * 256 + 2 * 256 * 128 + 768 * 256 + 2 * 768 * 512;
        pack_all<<<DIV_UP(total, 256), 256, 0, stream>>>(p);
    }

    // ---- G precompute (MFMA): G[s][pix][256] = ft_m @ W-slice ----
    {
        MArgs m = {};
        m.sstr = GS;
        m.Ahi = ft0h; m.Alo = ft0l; m.lda = 256;
        m.Bhi = Bg0h; m.Blo = Bg0l; m.K = 256;
        m.Y = Gbuf; m.V = 3136;
        dim3 g0(6, DIV_UP(3136, 64));
        mgemm<2><<<g0, 256, 0, stream>>>(m);
        m.Ahi = ft1h; m.Alo = ft1l; m.lda = 512;
        m.Bhi = Bg1h; m.Blo = Bg1l; m.K = 512;
        m.Y = Gbuf + (size_t)3136 * 256; m.V = 784;
        dim3 g1(6, DIV_UP(784, 64));
        mgemm<2><<<g1, 256, 0, stream>>>(m);
        m.Ahi = ft2h; m.Alo = ft2l; m.lda = 512;
        m.Bhi = Bg2h; m.Blo = Bg2l; m.K = 512;
        m.Y = Gbuf + (size_t)3920 * 256; m.V = 196;
        dim3 g2(6, DIV_UP(196, 64));
        mgemm<2><<<g2, 256, 0, stream>>>(m);
    }

    for (int si = 0; si < 3; ++si) {
        const float* Win0 = (const float*)d_in[6 + si * 9 + 0];
        const float* Win1 = (const float*)d_in[6 + si * 9 + 1];
        const float* bin = (const float*)d_in[6 + si * 9 + 2];
        const float* bs = (const float*)d_in[6 + si * 9 + 5];
        const float* Wc0 = (const float*)d_in[6 + si * 9 + 6];
        const float* Wc1 = (const float*)d_in[6 + si * 9 + 7];
        const float* bc = (const float*)d_in[6 + si * 9 + 8];
        const int* edges = (const int*)d_in[33 + si];
        int Ecur = E[si];
        const int* esrc = edges;
        const int* edst = edges + Ecur;
        int V = Vs[si];
        const float* vertsin = (si == 0) ? verts0 : vertsbuf;

        desc_adj_kernel<<<DIV_UP(V, 256), 256, 0, stream>>>(vertsin, cam_c, cam_f, imgsz, V,
                                                            esrc, edst, Ecur, sampi, sampw, adj8);
        // shape GEMM first (pure store), then gather adds perceptual part
        if (si > 0) {
            MArgs m = {};
            m.Ahi = FPhi; m.Alo = FPlo; m.lda = 128;
            m.Bhi = BtShi[si - 1]; m.Blo = BtSlo[si - 1]; m.K = 128;
            m.Y = Ybuf; m.V = V;
            dim3 grid(2, DIV_UP(V, 64));
            mgemm<3><<<grid, 256, 0, stream>>>(m);
        }
        gather_kernel<<<DIV_UP(V, 4), 256, 0, stream>>>(Gbuf, GS, sampi, sampw, Ybuf, V, si,
                                                        Win0, Win1, (si == 0) ? verts0 : nullptr);
        combine_in<<<DIV_UP(V, 8), 256, 0, stream>>>(Ybuf, bin, adj8, hA, V);

        float* hcur = hA;
        float* hnext = hB;
        for (int ll = 0; ll < 12; ++ll) {
            LArgs a = {};
            a.h = hcur;
            a.Bhi = BtLhi[si] + (size_t)ll * 32768;
            a.Blo = BtLlo[si] + (size_t)ll * 32768;
            a.adj8 = adj8;
            a.bias = bs + (size_t)ll * 128;
            a.hnext = hnext;
            a.V = V;
            lay_kernel<<<DIV_UP(V, 64), 256, 0, stream>>>(a);
            float* t = hcur; hcur = hnext; hnext = t;
        }

        coordgemm_kernel<<<DIV_UP(V * 6, 256), 256, 0, stream>>>(hcur, Wc0, Wc1, V, Yc);
        float* ctarget = (si == 2) ? (float*)d_out : vertsbuf;
        coordcombine_kernel<<<DIV_UP(V * 3, 256), 256, 0, stream>>>(Yc, bc, adj8, V, ctarget);
        if (si < 2) {
            const int* mid = (const int*)d_in[36 + si];
            int Nm = (si == 0) ? Nm0 : Nm1;
            unpool_kernel<<<V + Nm, 128, 0, stream>>>(vertsbuf, hcur, mid, V, Nm, FPhi, FPlo);
        }
    }
}

// Round 7
// 2015.319 us; speedup vs baseline: 1.0574x; 1.0574x over previous
//
#include <hip/hip_runtime.h>
#include <hip/hip_bf16.h>
#include <cstddef>
#include <cstdint>

#define DIV_UP(a, b) (((a) + (b) - 1) / (b))

typedef __attribute__((ext_vector_type(8))) short bf16x8v;
typedef __attribute__((ext_vector_type(4))) float f32x4v;

__device__ __forceinline__ unsigned short bf16_rn(float v) {
    unsigned int u = __float_as_uint(v);
    unsigned int r = (u + 0x7FFFu + ((u >> 16) & 1u)) >> 16;
    return (unsigned short)r;
}
__device__ __forceinline__ float bf16_f(unsigned short h) {
    return __uint_as_float(((unsigned int)h) << 16);
}
__device__ __forceinline__ void f2hl(float v, unsigned short& hi, unsigned short& lo) {
    hi = bf16_rn(v);
    float r = v - bf16_f(hi);
    lo = bf16_rn(r);
}
__device__ __forceinline__ int xcd_swz(int orig, int nwg) {
    int q = nwg >> 3, r = nwg & 7;
    int xcd = orig & 7, idx = orig >> 3;
    return (xcd < r ? xcd * (q + 1) : r * (q + 1) + (xcd - r) * q) + idx;
}

// ---------------- transpose (C,H,W) f32 -> (H*W, C) bf16 hi/lo --------------
__global__ void transpose_hl(const float* __restrict__ in, unsigned short* __restrict__ ohi,
                             unsigned short* __restrict__ olo, int C, int HW) {
    int idx = blockIdx.x * 256 + threadIdx.x;
    if (idx >= C * HW) return;
    int c = idx % C;
    int p = idx / C;
    float v = in[(size_t)c * HW + p];
    unsigned short hi, lo;
    f2hl(v, hi, lo);
    ohi[(size_t)p * C + c] = hi;
    olo[(size_t)p * C + c] = lo;
}

// ---------------- single fused weight-pack kernel ---------------------------
// Layer weights now packed in MFMA-fragment order:
//   BtLp[st][layer][ks(8)][nt(8)][hl(2)][lane(64)][i(8)]
// fragment value = Bt[n = nt*16+(lane&15)][k = ks*32+(lane>>4)*8+i]
struct PackArgs {
    const float* Win0[3]; const float* Win1[3];   // [1408|1283][128]
    const float* W0L[3];  const float* W1L[3];    // [12][128][128]
    unsigned short* BtLp[3];                      // [12][64][2][512]
    unsigned short *BtShi[2], *BtSlo[2];          // stages 1,2: [256][128]
    unsigned short *Bgh[3], *Bgl[3];              // [768][C] C=256,512,512
};

__global__ void pack_all(PackArgs p) {
    const int LAY1 = 12 * 32768;               // 393216 per stage
    const int LAYT = 3 * LAY1;                 // 1179648
    const int SH1 = 256 * 128;                 // 32768 per stage
    const int SHT = 2 * SH1;
    const int GB0 = 768 * 256, GB1 = 768 * 512;
    int idx = blockIdx.x * 256 + threadIdx.x;
    if (idx < LAYT) {
        int st = idx / LAY1, r = idx % LAY1;
        int layer = r >> 15, q = r & 32767;
        int ks = q >> 12, nt = (q >> 9) & 7, lane = (q >> 3) & 63, i = q & 7;
        int n = nt * 16 + (lane & 15);
        int k = ks * 32 + ((lane >> 4) << 3) + i;
        float v = (k < 128) ? p.W0L[st][(size_t)layer * 16384 + k * 128 + n]
                            : p.W1L[st][(size_t)layer * 16384 + (k - 128) * 128 + n];
        unsigned short hi, lo;
        f2hl(v, hi, lo);
        size_t base = ((size_t)layer * 64 + ks * 8 + nt) * 1024 + lane * 8 + i;
        p.BtLp[st][base] = hi;
        p.BtLp[st][base + 512] = lo;
        return;
    }
    float v;
    unsigned short* dh;
    unsigned short* dl;
    size_t o;
    if (idx < LAYT + SHT) {
        int q = idx - LAYT;
        int st = q / SH1, rr = q % SH1;
        int n = rr >> 7, k = rr & 127;
        const float* w0 = p.Win0[st + 1];
        const float* w1 = p.Win1[st + 1];
        v = (n < 128) ? w0[(size_t)(1280 + k) * 128 + n]
                      : w1[(size_t)(1280 + k) * 128 + (n - 128)];
        dh = p.BtShi[st]; dl = p.BtSlo[st]; o = rr;
    } else {
        int q = idx - LAYT - SHT;
        int m, C, base;
        if (q < GB0) { m = 0; C = 256; base = 0; }
        else if (q < GB0 + GB1) { m = 1; C = 512; base = 256; q -= GB0; }
        else if (q < GB0 + 2 * GB1) { m = 2; C = 512; base = 768; q -= GB0 + GB1; }
        else return;
        int n = q / C, k = q % C;
        int s = n >> 8, j = n & 255;
        v = (j < 128) ? p.Win0[s][(size_t)(base + k) * 128 + j]
                      : p.Win1[s][(size_t)(base + k) * 128 + (j - 128)];
        dh = p.Bgh[m]; dl = p.Bgl[m]; o = q;
    }
    unsigned short hi, lo;
    f2hl(v, hi, lo);
    dh[o] = hi;
    dl[o] = lo;
}

// -------- per-vertex projection/bilerp descriptors + fixed-degree adj -------
__global__ void desc_adj_kernel(const float* __restrict__ verts,
                                const float* __restrict__ cam_c, const float* __restrict__ cam_f,
                                const int* __restrict__ imgsz, int V,
                                const int* __restrict__ src, const int* __restrict__ dst, int E,
                                int* __restrict__ sampi, float* __restrict__ sampw,
                                int* __restrict__ adj8) {
    int v = blockIdx.x * 256 + threadIdx.x;
    if (v >= V) return;
    float X = verts[3 * v + 0], Yy = verts[3 * v + 1], Z = verts[3 * v + 2];
    float cx = cam_c[0], cy = cam_c[1], fx = cam_f[0], fy = cam_f[1];
    const float tz = 0.8f;
    float pz = Z + tz;
    float px = (fx * X + cx * Z + tz * cx) / pz;
    float py = (fy * Yy + cy * Z + tz * cy) / pz;
    float is = (float)imgsz[0];
    const int Ss[3] = {56, 28, 14};
#pragma unroll
    for (int m = 0; m < 3; ++m) {
        int S = Ss[m];
        float dim = (float)S;
        float x = px * dim / is;
        float y = py * dim / is;
        float x1 = floorf(x), y1 = floorf(y);
        float x2 = x1 + 1.0f, y2 = y1 + 1.0f;
        float smax = (float)(S - 1);
        int xi1 = (int)fminf(fmaxf(x1, 0.0f), smax);
        int xi2 = (int)fminf(fmaxf(x2, 0.0f), smax);
        int yi1 = (int)fminf(fmaxf(y1, 0.0f), smax);
        int yi2 = (int)fminf(fmaxf(y2, 0.0f), smax);
        int b = v * 12 + m * 4;
        sampi[b + 0] = xi1 * S + yi1;
        sampi[b + 1] = xi1 * S + yi2;
        sampi[b + 2] = xi2 * S + yi1;
        sampi[b + 3] = xi2 * S + yi2;
        sampw[b + 0] = (x2 - x) * (y2 - y);
        sampw[b + 1] = (x2 - x) * (y - y1);
        sampw[b + 2] = (x - x1) * (y2 - y);
        sampw[b + 3] = (x - x1) * (y - y1);
    }
    // fixed-degree adjacency via two binary searches on sorted src
    int lo = 0, hi = E;
    while (lo < hi) { int m = (lo + hi) >> 1; if (src[m] < v) lo = m + 1; else hi = m; }
    int e0 = lo;
    hi = E;
    while (lo < hi) { int m = (lo + hi) >> 1; if (src[m] < v + 1) lo = m + 1; else hi = m; }
    int e1 = lo;
    int* ap = adj8 + (size_t)v * 8;
#pragma unroll
    for (int i = 0; i < 8; ++i) {
        int e = e0 + i;
        ap[i] = (e < e1) ? dst[e] : -1;
    }
}

// ---------------- MFMA bf16x3 GEMM (G precompute + shape GEMM) --------------
struct MArgs {
    const unsigned short *Ahi, *Alo; int lda;
    const unsigned short *Bhi, *Blo; int K;  // Bt row-major [N][K]
    float* Y;
    int sstr;
    int V;
};

template <int EPI>
__global__ __launch_bounds__(256) void mgemm(MArgs g) {
    __shared__ unsigned short As_hi[64][40], As_lo[64][40];
    __shared__ unsigned short Bs_hi[128][40], Bs_lo[128][40];
    int tid = threadIdx.x;
    int row0 = blockIdx.y * 64;
    int col0 = blockIdx.x * 128;
    int l = tid & 63, wid = tid >> 6;
    int wr = wid & 1, wc = wid >> 1;
    int lw = l & 15, gg = l >> 4;
    f32x4v acc[2][4];
#pragma unroll
    for (int i = 0; i < 2; ++i)
#pragma unroll
        for (int j = 0; j < 4; ++j) acc[i][j] = (f32x4v){0.f, 0.f, 0.f, 0.f};

    int arow = tid >> 2, akoff = (tid & 3) * 8;
    for (int k0 = 0; k0 < g.K; k0 += 32) {
        __syncthreads();
        {
            int grow = row0 + arow;
            uint4 zh = make_uint4(0, 0, 0, 0), zl = make_uint4(0, 0, 0, 0);
            if (grow < g.V) {
                zh = *(const uint4*)(g.Ahi + (size_t)grow * g.lda + k0 + akoff);
                zl = *(const uint4*)(g.Alo + (size_t)grow * g.lda + k0 + akoff);
            }
            *(uint4*)&As_hi[arow][akoff] = zh;
            *(uint4*)&As_lo[arow][akoff] = zl;
        }
#pragma unroll
        for (int it = 0; it < 2; ++it) {
            int q = tid + it * 256;
            int n = q >> 2, koff = (q & 3) * 8;
            *(uint4*)&Bs_hi[n][koff] = *(const uint4*)(g.Bhi + (size_t)(col0 + n) * g.K + k0 + koff);
            *(uint4*)&Bs_lo[n][koff] = *(const uint4*)(g.Blo + (size_t)(col0 + n) * g.K + k0 + koff);
        }
        __syncthreads();
        bf16x8v ah[2], al[2], bh[4], bl[4];
#pragma unroll
        for (int mt = 0; mt < 2; ++mt) {
            int r = wr * 32 + mt * 16 + lw;
            ah[mt] = *(const bf16x8v*)&As_hi[r][gg * 8];
            al[mt] = *(const bf16x8v*)&As_lo[r][gg * 8];
        }
#pragma unroll
        for (int nt = 0; nt < 4; ++nt) {
            int c = wc * 64 + nt * 16 + lw;
            bh[nt] = *(const bf16x8v*)&Bs_hi[c][gg * 8];
            bl[nt] = *(const bf16x8v*)&Bs_lo[c][gg * 8];
        }
#pragma unroll
        for (int mt = 0; mt < 2; ++mt)
#pragma unroll
            for (int nt = 0; nt < 4; ++nt) {
                acc[mt][nt] = __builtin_amdgcn_mfma_f32_16x16x32_bf16(ah[mt], bh[nt], acc[mt][nt], 0, 0, 0);
                acc[mt][nt] = __builtin_amdgcn_mfma_f32_16x16x32_bf16(ah[mt], bl[nt], acc[mt][nt], 0, 0, 0);
                acc[mt][nt] = __builtin_amdgcn_mfma_f32_16x16x32_bf16(al[mt], bh[nt], acc[mt][nt], 0, 0, 0);
            }
    }
#pragma unroll
    for (int mt = 0; mt < 2; ++mt)
#pragma unroll
        for (int nt = 0; nt < 4; ++nt) {
            int colg = wc * 64 + nt * 16 + lw;
#pragma unroll
            for (int r = 0; r < 4; ++r) {
                int rowg = row0 + wr * 32 + mt * 16 + gg * 4 + r;
                if (rowg >= g.V) continue;
                float v = acc[mt][nt][r];
                if (EPI == 3) {
                    g.Y[(size_t)rowg * 256 + col0 + colg] = v;
                } else {
                    int cg = col0 + colg;
                    g.Y[(size_t)(cg >> 8) * g.sstr + (size_t)rowg * 256 + (cg & 255)] = v;
                }
            }
        }
}

// ---------------- input perceptual gather (float4, 64 thr/vertex) -----------
__global__ void gather_kernel(const float* __restrict__ G, int sstr,
                              const int* __restrict__ sampi, const float* __restrict__ sampw,
                              float* __restrict__ Yb, int V, int stage,
                              const float* __restrict__ Win0, const float* __restrict__ Win1,
                              const float* __restrict__ shape) {
    int v = xcd_swz(blockIdx.x, gridDim.x) * 4 + (threadIdx.x >> 6);
    if (v >= V) return;
    int j = (threadIdx.x & 63) * 4;
    const float* Gs = G + (size_t)stage * sstr;
    int b = v * 12;
    float4 acc;
    if (stage == 0) acc = make_float4(0.f, 0.f, 0.f, 0.f);
    else acc = *(const float4*)(Yb + (size_t)v * 256 + j);
#pragma unroll
    for (int s = 0; s < 4; ++s) {
        float w = sampw[b + s];
        float4 f = *(const float4*)(Gs + (size_t)sampi[b + s] * 256 + j);
        acc.x += w * f.x; acc.y += w * f.y; acc.z += w * f.z; acc.w += w * f.w;
    }
#pragma unroll
    for (int s = 0; s < 4; ++s) {
        float w = sampw[b + 4 + s];
        float4 f = *(const float4*)(Gs + (size_t)(3136 + sampi[b + 4 + s]) * 256 + j);
        acc.x += w * f.x; acc.y += w * f.y; acc.z += w * f.z; acc.w += w * f.w;
    }
#pragma unroll
    for (int s = 0; s < 4; ++s) {
        float w = sampw[b + 8 + s];
        float4 f = *(const float4*)(Gs + (size_t)(3920 + sampi[b + 8 + s]) * 256 + j);
        acc.x += w * f.x; acc.y += w * f.y; acc.z += w * f.z; acc.w += w * f.w;
    }
    if (stage == 0) {
#pragma unroll
        for (int k = 0; k < 3; ++k) {
            float w = shape[v * 3 + k];
            const float* wr = (j < 128) ? Win0 + (size_t)(1280 + k) * 128 + j
                                        : Win1 + (size_t)(1280 + k) * 128 + (j - 128);
            float4 wv = *(const float4*)wr;
            acc.x += w * wv.x; acc.y += w * wv.y; acc.z += w * wv.z; acc.w += w * wv.w;
        }
    }
    *(float4*)(Yb + (size_t)v * 256 + j) = acc;
}

// ---------------- input-layer combine (float4, 32 thr/vertex) ---------------
__global__ __launch_bounds__(256) void combine_in(
    const float* __restrict__ Y, const float* __restrict__ bias,
    const int* __restrict__ adj8,
    float* __restrict__ hout, int V) {
    int v = xcd_swz(blockIdx.x, gridDim.x) * 8 + (threadIdx.x >> 5);
    if (v >= V) return;
    int d = (threadIdx.x & 31) * 4;
    float4 val = *(const float4*)(Y + (size_t)v * 256 + d);
    float4 b4 = *(const float4*)(bias + d);
    val.x += b4.x; val.y += b4.y; val.z += b4.z; val.w += b4.w;
    const int* ap = adj8 + (size_t)v * 8;
    int n[6];
#pragma unroll
    for (int i = 0; i < 6; ++i) n[i] = ap[i];
#pragma unroll
    for (int i = 0; i < 6; ++i) {
        if (n[i] >= 0) {
            float4 f = *(const float4*)(Y + (size_t)n[i] * 256 + 128 + d);
            val.x += f.x; val.y += f.y; val.z += f.z; val.w += f.w;
        }
    }
    val.x = fmaxf(val.x, 0.f); val.y = fmaxf(val.y, 0.f);
    val.z = fmaxf(val.z, 0.f); val.w = fmaxf(val.w, 0.f);
    *(float4*)(hout + (size_t)v * 128 + d) = val;
}

// ---------------- fused resnet layer: no LDS/barriers, packed-fragment B ----
// Wave = 32 rows (two 16-row subtiles). B fragments pre-packed so each load is
// a fully-coalesced 1KB wave transaction: Bp + ((ks*8+nt)*2+hl)*512 + l*8.
struct LArgs {
    const float* h;                                   // [V][128] f32
    const unsigned short* Bp;                         // packed [64][2][512]
    const int* adj8;
    const float* bias;
    float* hnext;
    int V;
};

__global__ __launch_bounds__(256) void lay_kernel(LArgs g) {
    int tid = threadIdx.x;
    int wid = tid >> 6, l = tid & 63;
    int w = xcd_swz(blockIdx.x, gridDim.x) * 4 + wid;
    int rowbase = w * 32;
    int lrow = l & 15, lks = l >> 4;
    int grow0 = rowbase + lrow;
    int grow1 = rowbase + 16 + lrow;

    f32x4v acc[2][8];
#pragma unroll
    for (int m = 0; m < 2; ++m)
#pragma unroll
        for (int nt = 0; nt < 8; ++nt) acc[m][nt] = (f32x4v){0.f, 0.f, 0.f, 0.f};

    int n0[6], n1[6];
    if (grow0 < g.V) {
        const int* ap = g.adj8 + (size_t)grow0 * 8;
#pragma unroll
        for (int i = 0; i < 6; ++i) n0[i] = ap[i];
    } else {
#pragma unroll
        for (int i = 0; i < 6; ++i) n0[i] = -1;
    }
    if (grow1 < g.V) {
        const int* ap = g.adj8 + (size_t)grow1 * 8;
#pragma unroll
        for (int i = 0; i < 6; ++i) n1[i] = ap[i];
    } else {
#pragma unroll
        for (int i = 0; i < 6; ++i) n1[i] = -1;
    }

#pragma unroll
    for (int ks = 0; ks < 8; ++ks) {
        // ---- coalesced B fragment loads (16 x 1KB wave transactions) ----
        bf16x8v bh[8], bl[8];
#pragma unroll
        for (int nt = 0; nt < 8; ++nt) {
            const unsigned short* p = g.Bp + ((size_t)(ks * 8 + nt)) * 1024 + l * 8;
            bh[nt] = *(const bf16x8v*)p;
            bl[nt] = *(const bf16x8v*)(p + 512);
        }
        int ko = (ks & 3) * 32 + lks * 8;  // k-offset within 128-wide half
#pragma unroll
        for (int m = 0; m < 2; ++m) {
            int grow = m ? grow1 : grow0;
            float a[8];
            if (ks < 4) {
                // own half
                if (grow < g.V) {
                    const float* hp = g.h + (size_t)grow * 128 + ko;
                    float4 f0 = *(const float4*)hp;
                    float4 f1 = *(const float4*)(hp + 4);
                    a[0] = f0.x; a[1] = f0.y; a[2] = f0.z; a[3] = f0.w;
                    a[4] = f1.x; a[5] = f1.y; a[6] = f1.z; a[7] = f1.w;
                } else {
#pragma unroll
                    for (int i = 0; i < 8; ++i) a[i] = 0.f;
                }
            } else {
                // agg half: sum <=6 independent neighbor-row slices
#pragma unroll
                for (int i = 0; i < 8; ++i) a[i] = 0.f;
                const int* nn = m ? n1 : n0;
#pragma unroll
                for (int i = 0; i < 6; ++i) {
                    if (nn[i] >= 0) {
                        const float* hp = g.h + (size_t)nn[i] * 128 + ko;
                        float4 f0 = *(const float4*)hp;
                        float4 f1 = *(const float4*)(hp + 4);
                        a[0] += f0.x; a[1] += f0.y; a[2] += f0.z; a[3] += f0.w;
                        a[4] += f1.x; a[5] += f1.y; a[6] += f1.z; a[7] += f1.w;
                    }
                }
            }
            unsigned short hh[8], ll[8];
#pragma unroll
            for (int i = 0; i < 8; ++i) f2hl(a[i], hh[i], ll[i]);
            bf16x8v ah = *(const bf16x8v*)hh;
            bf16x8v al = *(const bf16x8v*)ll;
#pragma unroll
            for (int nt = 0; nt < 8; ++nt) {
                acc[m][nt] = __builtin_amdgcn_mfma_f32_16x16x32_bf16(ah, bh[nt], acc[m][nt], 0, 0, 0);
                acc[m][nt] = __builtin_amdgcn_mfma_f32_16x16x32_bf16(ah, bl[nt], acc[m][nt], 0, 0, 0);
                acc[m][nt] = __builtin_amdgcn_mfma_f32_16x16x32_bf16(al, bh[nt], acc[m][nt], 0, 0, 0);
            }
        }
    }

    // ---- epilogue: hnext = relu(acc + bias) + h ----
#pragma unroll
    for (int m = 0; m < 2; ++m)
#pragma unroll
        for (int nt = 0; nt < 8; ++nt) {
            int colg = nt * 16 + lrow;
            float bv = g.bias[colg];
#pragma unroll
            for (int r = 0; r < 4; ++r) {
                int rowg = rowbase + m * 16 + lks * 4 + r;
                if (rowg < g.V) {
                    float v = acc[m][nt][r] + bv;
                    v = fmaxf(v, 0.0f);
                    v += g.h[(size_t)rowg * 128 + colg];
                    g.hnext[(size_t)rowg * 128 + colg] = v;
                }
            }
        }
}

// ---------------- coord head ------------------------------------------------
__global__ void coordgemm_kernel(const float* __restrict__ h,
                                 const float* __restrict__ Wc0, const float* __restrict__ Wc1,
                                 int V, float* __restrict__ Yc) {
    int idx = blockIdx.x * 256 + threadIdx.x;
    if (idx >= V * 6) return;
    int v = idx / 6, j = idx % 6;
    const float* W = (j < 3) ? Wc0 : Wc1;
    int jj = (j < 3) ? j : j - 3;
    const float* hp = h + (size_t)v * 128;
    float acc = 0.0f;
#pragma unroll
    for (int k = 0; k < 32; ++k) {
        float4 f = *(const float4*)(hp + k * 4);
        acc += f.x * W[(k * 4 + 0) * 3 + jj];
        acc += f.y * W[(k * 4 + 1) * 3 + jj];
        acc += f.z * W[(k * 4 + 2) * 3 + jj];
        acc += f.w * W[(k * 4 + 3) * 3 + jj];
    }
    Yc[idx] = acc;
}

__global__ void coordcombine_kernel(const float* __restrict__ Yc, const float* __restrict__ bc,
                                    const int* __restrict__ adj8,
                                    int V, float* __restrict__ out) {
    int idx = blockIdx.x * 256 + threadIdx.x;
    if (idx >= V * 3) return;
    int v = idx / 3, j = idx % 3;
    float val = Yc[(size_t)v * 6 + j] + bc[j];
    const int* ap = adj8 + (size_t)v * 8;
    int n[6];
#pragma unroll
    for (int i = 0; i < 6; ++i) n[i] = ap[i];
#pragma unroll
    for (int i = 0; i < 6; ++i)
        if (n[i] >= 0) val += Yc[(size_t)n[i] * 6 + 3 + j];
    out[(size_t)v * 3 + j] = val;
}

// ---------------- unpool: verts midpoints + featpack hi/lo ------------------
__global__ void unpool_kernel(float* __restrict__ verts, const float* __restrict__ h,
                              const int* __restrict__ mid, int V, int Nm,
                              unsigned short* __restrict__ fphi, unsigned short* __restrict__ fplo) {
    int r = blockIdx.x;
    int t = threadIdx.x;  // 128
    if (r < V) {
        float v = h[(size_t)r * 128 + t];
        unsigned short hi, lo;
        f2hl(v, hi, lo);
        fphi[(size_t)r * 128 + t] = hi;
        fplo[(size_t)r * 128 + t] = lo;
    } else {
        int i = r - V;
        int a = mid[2 * i], b = mid[2 * i + 1];
        float v = 0.5f * (h[(size_t)a * 128 + t] + h[(size_t)b * 128 + t]);
        unsigned short hi, lo;
        f2hl(v, hi, lo);
        fphi[(size_t)r * 128 + t] = hi;
        fplo[(size_t)r * 128 + t] = lo;
        if (t < 3)
            verts[(size_t)r * 3 + t] = 0.5f * (verts[(size_t)a * 3 + t] + verts[(size_t)b * 3 + t]);
    }
}

// ---------------------------------------------------------------------------
extern "C" void kernel_launch(void* const* d_in, const int* in_sizes, int n_in,
                              void* d_out, int out_size, void* d_ws, size_t ws_size,
                              hipStream_t stream) {
    const float* f3 = (const float*)d_in[0];
    const float* f4 = (const float*)d_in[1];
    const float* f5 = (const float*)d_in[2];
    const float* verts0 = (const float*)d_in[3];
    const float* cam_c = (const float*)d_in[4];
    const float* cam_f = (const float*)d_in[5];
    const int* imgsz = (const int*)d_in[38];

    int V0 = in_sizes[3] / 3;
    int E[3] = {in_sizes[33] / 2, in_sizes[34] / 2, in_sizes[35] / 2};
    int Nm0 = in_sizes[36] / 2, Nm1 = in_sizes[37] / 2;
    int V1 = V0 + Nm0, V2 = V1 + Nm1;
    int Vs[3] = {V0, V1, V2};
    const int NPIXT = 3136 + 784 + 196;  // 4116
    const int GS = NPIXT * 256;          // per-stage G stride (floats)

    // ---- workspace (byte allocator, 256B aligned) ----
    char* wsp = (char*)d_ws;
    auto alloc = [&](size_t bytes) -> void* {
        void* p = (void*)wsp;
        wsp += (bytes + 255) & ~(size_t)255;
        return p;
    };
    unsigned short* ft0h = (unsigned short*)alloc((size_t)3136 * 256 * 2);
    unsigned short* ft0l = (unsigned short*)alloc((size_t)3136 * 256 * 2);
    unsigned short* ft1h = (unsigned short*)alloc((size_t)784 * 512 * 2);
    unsigned short* ft1l = (unsigned short*)alloc((size_t)784 * 512 * 2);
    unsigned short* ft2h = (unsigned short*)alloc((size_t)196 * 512 * 2);
    unsigned short* ft2l = (unsigned short*)alloc((size_t)196 * 512 * 2);
    unsigned short* Bg0h = (unsigned short*)alloc((size_t)768 * 256 * 2);
    unsigned short* Bg0l = (unsigned short*)alloc((size_t)768 * 256 * 2);
    unsigned short* Bg1h = (unsigned short*)alloc((size_t)768 * 512 * 2);
    unsigned short* Bg1l = (unsigned short*)alloc((size_t)768 * 512 * 2);
    unsigned short* Bg2h = (unsigned short*)alloc((size_t)768 * 512 * 2);
    unsigned short* Bg2l = (unsigned short*)alloc((size_t)768 * 512 * 2);
    float* Gbuf = (float*)alloc((size_t)3 * GS * 4);
    unsigned short* BtLp[3];
    for (int s = 0; s < 3; ++s)
        BtLp[s] = (unsigned short*)alloc((size_t)12 * 65536 * 2);  // fragment-packed hi+lo
    unsigned short* BtShi[2];
    unsigned short* BtSlo[2];
    for (int s = 0; s < 2; ++s) {
        BtShi[s] = (unsigned short*)alloc((size_t)256 * 128 * 2);
        BtSlo[s] = (unsigned short*)alloc((size_t)256 * 128 * 2);
    }
    float* Ybuf = (float*)alloc((size_t)V2 * 256 * 4);
    float* hA = (float*)alloc((size_t)V2 * 128 * 4);
    float* hB = (float*)alloc((size_t)V2 * 128 * 4);
    unsigned short* FPhi = (unsigned short*)alloc((size_t)V2 * 128 * 2);
    unsigned short* FPlo = (unsigned short*)alloc((size_t)V2 * 128 * 2);
    float* vertsbuf = (float*)alloc((size_t)V2 * 3 * 4);
    float* Yc = (float*)alloc((size_t)V2 * 6 * 4);
    int* sampi = (int*)alloc((size_t)V2 * 12 * 4);
    float* sampw = (float*)alloc((size_t)V2 * 12 * 4);
    int* adj8 = (int*)alloc((size_t)V2 * 8 * 4);

    // ---- feature map transpose + hi/lo split ----
    transpose_hl<<<DIV_UP(256 * 56 * 56, 256), 256, 0, stream>>>(f3, ft0h, ft0l, 256, 56 * 56);
    transpose_hl<<<DIV_UP(512 * 28 * 28, 256), 256, 0, stream>>>(f4, ft1h, ft1l, 512, 28 * 28);
    transpose_hl<<<DIV_UP(512 * 14 * 14, 256), 256, 0, stream>>>(f5, ft2h, ft2l, 512, 14 * 14);

    // ---- single fused weight pack ----
    {
        PackArgs p;
        for (int s = 0; s < 3; ++s) {
            p.Win0[s] = (const float*)d_in[6 + s * 9 + 0];
            p.Win1[s] = (const float*)d_in[6 + s * 9 + 1];
            p.W0L[s] = (const float*)d_in[6 + s * 9 + 3];
            p.W1L[s] = (const float*)d_in[6 + s * 9 + 4];
            p.BtLp[s] = BtLp[s];
        }
        p.BtShi[0] = BtShi[0]; p.BtSlo[0] = BtSlo[0];
        p.BtShi[1] = BtShi[1]; p.BtSlo[1] = BtSlo[1];
        p.Bgh[0] = Bg0h; p.Bgl[0] = Bg0l;
        p.Bgh[1] = Bg1h; p.Bgl[1] = Bg1l;
        p.Bgh[2] = Bg2h; p.Bgl[2] = Bg2l;
        int total = 3 * 12 * 32768 + 2 * 256 * 128 + 768 * 256 + 2 * 768 * 512;
        pack_all<<<DIV_UP(total, 256), 256, 0, stream>>>(p);
    }

    // ---- G precompute (MFMA): G[s][pix][256] = ft_m @ W-slice ----
    {
        MArgs m = {};
        m.sstr = GS;
        m.Ahi = ft0h; m.Alo = ft0l; m.lda = 256;
        m.Bhi = Bg0h; m.Blo = Bg0l; m.K = 256;
        m.Y = Gbuf; m.V = 3136;
        dim3 g0(6, DIV_UP(3136, 64));
        mgemm<2><<<g0, 256, 0, stream>>>(m);
        m.Ahi = ft1h; m.Alo = ft1l; m.lda = 512;
        m.Bhi = Bg1h; m.Blo = Bg1l; m.K = 512;
        m.Y = Gbuf + (size_t)3136 * 256; m.V = 784;
        dim3 g1(6, DIV_UP(784, 64));
        mgemm<2><<<g1, 256, 0, stream>>>(m);
        m.Ahi = ft2h; m.Alo = ft2l; m.lda = 512;
        m.Bhi = Bg2h; m.Blo = Bg2l; m.K = 512;
        m.Y = Gbuf + (size_t)3920 * 256; m.V = 196;
        dim3 g2(6, DIV_UP(196, 64));
        mgemm<2><<<g2, 256, 0, stream>>>(m);
    }

    for (int si = 0; si < 3; ++si) {
        const float* Win0 = (const float*)d_in[6 + si * 9 + 0];
        const float* Win1 = (const float*)d_in[6 + si * 9 + 1];
        const float* bin = (const float*)d_in[6 + si * 9 + 2];
        const float* bs = (const float*)d_in[6 + si * 9 + 5];
        const float* Wc0 = (const float*)d_in[6 + si * 9 + 6];
        const float* Wc1 = (const float*)d_in[6 + si * 9 + 7];
        const float* bc = (const float*)d_in[6 + si * 9 + 8];
        const int* edges = (const int*)d_in[33 + si];
        int Ecur = E[si];
        const int* esrc = edges;
        const int* edst = edges + Ecur;
        int V = Vs[si];
        const float* vertsin = (si == 0) ? verts0 : vertsbuf;

        desc_adj_kernel<<<DIV_UP(V, 256), 256, 0, stream>>>(vertsin, cam_c, cam_f, imgsz, V,
                                                            esrc, edst, Ecur, sampi, sampw, adj8);
        // shape GEMM first (pure store), then gather adds perceptual part
        if (si > 0) {
            MArgs m = {};
            m.Ahi = FPhi; m.Alo = FPlo; m.lda = 128;
            m.Bhi = BtShi[si - 1]; m.Blo = BtSlo[si - 1]; m.K = 128;
            m.Y = Ybuf; m.V = V;
            dim3 grid(2, DIV_UP(V, 64));
            mgemm<3><<<grid, 256, 0, stream>>>(m);
        }
        gather_kernel<<<DIV_UP(V, 4), 256, 0, stream>>>(Gbuf, GS, sampi, sampw, Ybuf, V, si,
                                                        Win0, Win1, (si == 0) ? verts0 : nullptr);
        combine_in<<<DIV_UP(V, 8), 256, 0, stream>>>(Ybuf, bin, adj8, hA, V);

        float* hcur = hA;
        float* hnext = hB;
        for (int ll = 0; ll < 12; ++ll) {
            LArgs a = {};
            a.h = hcur;
            a.Bp = BtLp[si] + (size_t)ll * 65536;
            a.adj8 = adj8;
            a.bias = bs + (size_t)ll * 128;
            a.hnext = hnext;
            a.V = V;
            lay_kernel<<<DIV_UP(V, 128), 256, 0, stream>>>(a);
            float* t = hcur; hcur = hnext; hnext = t;
        }

        coordgemm_kernel<<<DIV_UP(V * 6, 256), 256, 0, stream>>>(hcur, Wc0, Wc1, V, Yc);
        float* ctarget = (si == 2) ? (float*)d_out : vertsbuf;
        coordcombine_kernel<<<DIV_UP(V * 3, 256), 256, 0, stream>>>(Yc, bc, adj8, V, ctarget);
        if (si < 2) {
            const int* mid = (const int*)d_in[36 + si];
            int Nm = (si == 0) ? Nm0 : Nm1;
            unpool_kernel<<<V + Nm, 128, 0, stream>>>(vertsbuf, hcur, mid, V, Nm, FPhi, FPlo);
        }
    }
}

// Round 8
// 1409.495 us; speedup vs baseline: 1.5118x; 1.4298x over previous
//
#include <hip/hip_runtime.h>
#include <hip/hip_bf16.h>
#include <cstddef>
#include <cstdint>

#define DIV_UP(a, b) (((a) + (b) - 1) / (b))

typedef __attribute__((ext_vector_type(8))) short bf16x8v;
typedef __attribute__((ext_vector_type(4))) float f32x4v;

__device__ __forceinline__ unsigned short bf16_rn(float v) {
    unsigned int u = __float_as_uint(v);
    unsigned int r = (u + 0x7FFFu + ((u >> 16) & 1u)) >> 16;
    return (unsigned short)r;
}
__device__ __forceinline__ float bf16_f(unsigned short h) {
    return __uint_as_float(((unsigned int)h) << 16);
}
__device__ __forceinline__ void f2hl(float v, unsigned short& hi, unsigned short& lo) {
    hi = bf16_rn(v);
    float r = v - bf16_f(hi);
    lo = bf16_rn(r);
}
__device__ __forceinline__ int xcd_swz(int orig, int nwg) {
    int q = nwg >> 3, r = nwg & 7;
    int xcd = orig & 7, idx = orig >> 3;
    return (xcd < r ? xcd * (q + 1) : r * (q + 1) + (xcd - r) * q) + idx;
}

// ---------------- transpose (C,H,W) f32 -> (H*W, C) bf16 hi/lo --------------
__global__ void transpose_hl(const float* __restrict__ in, unsigned short* __restrict__ ohi,
                             unsigned short* __restrict__ olo, int C, int HW) {
    int idx = blockIdx.x * 256 + threadIdx.x;
    if (idx >= C * HW) return;
    int c = idx % C;
    int p = idx / C;
    float v = in[(size_t)c * HW + p];
    unsigned short hi, lo;
    f2hl(v, hi, lo);
    ohi[(size_t)p * C + c] = hi;
    olo[(size_t)p * C + c] = lo;
}

// ---------------- single fused weight-pack kernel ---------------------------
// Layer weights packed in MFMA-fragment order:
//   BtLp[st][layer][ks(8)][nt(8)][hl(2)][lane(64)][i(8)]
// fragment value = Bt[n = nt*16+(lane&15)][k = ks*32+(lane>>4)*8+i]
struct PackArgs {
    const float* Win0[3]; const float* Win1[3];   // [1408|1283][128]
    const float* W0L[3];  const float* W1L[3];    // [12][128][128]
    unsigned short* BtLp[3];                      // [12][64][2][512]
    unsigned short *BtShi[2], *BtSlo[2];          // stages 1,2: [256][128]
    unsigned short *Bgh[3], *Bgl[3];              // [768][C] C=256,512,512
};

__global__ void pack_all(PackArgs p) {
    const int LAY1 = 12 * 32768;               // 393216 per stage
    const int LAYT = 3 * LAY1;                 // 1179648
    const int SH1 = 256 * 128;                 // 32768 per stage
    const int SHT = 2 * SH1;
    const int GB0 = 768 * 256, GB1 = 768 * 512;
    int idx = blockIdx.x * 256 + threadIdx.x;
    if (idx < LAYT) {
        int st = idx / LAY1, r = idx % LAY1;
        int layer = r >> 15, q = r & 32767;
        int ks = q >> 12, nt = (q >> 9) & 7, lane = (q >> 3) & 63, i = q & 7;
        int n = nt * 16 + (lane & 15);
        int k = ks * 32 + ((lane >> 4) << 3) + i;
        float v = (k < 128) ? p.W0L[st][(size_t)layer * 16384 + k * 128 + n]
                            : p.W1L[st][(size_t)layer * 16384 + (k - 128) * 128 + n];
        unsigned short hi, lo;
        f2hl(v, hi, lo);
        size_t base = ((size_t)layer * 64 + ks * 8 + nt) * 1024 + lane * 8 + i;
        p.BtLp[st][base] = hi;
        p.BtLp[st][base + 512] = lo;
        return;
    }
    float v;
    unsigned short* dh;
    unsigned short* dl;
    size_t o;
    if (idx < LAYT + SHT) {
        int q = idx - LAYT;
        int st = q / SH1, rr = q % SH1;
        int n = rr >> 7, k = rr & 127;
        const float* w0 = p.Win0[st + 1];
        const float* w1 = p.Win1[st + 1];
        v = (n < 128) ? w0[(size_t)(1280 + k) * 128 + n]
                      : w1[(size_t)(1280 + k) * 128 + (n - 128)];
        dh = p.BtShi[st]; dl = p.BtSlo[st]; o = rr;
    } else {
        int q = idx - LAYT - SHT;
        int m, C, base;
        if (q < GB0) { m = 0; C = 256; base = 0; }
        else if (q < GB0 + GB1) { m = 1; C = 512; base = 256; q -= GB0; }
        else if (q < GB0 + 2 * GB1) { m = 2; C = 512; base = 768; q -= GB0 + GB1; }
        else return;
        int n = q / C, k = q % C;
        int s = n >> 8, j = n & 255;
        v = (j < 128) ? p.Win0[s][(size_t)(base + k) * 128 + j]
                      : p.Win1[s][(size_t)(base + k) * 128 + (j - 128)];
        dh = p.Bgh[m]; dl = p.Bgl[m]; o = q;
    }
    unsigned short hi, lo;
    f2hl(v, hi, lo);
    dh[o] = hi;
    dl[o] = lo;
}

// -------- per-vertex projection/bilerp descriptors + fixed-degree adj -------
__global__ void desc_adj_kernel(const float* __restrict__ verts,
                                const float* __restrict__ cam_c, const float* __restrict__ cam_f,
                                const int* __restrict__ imgsz, int V,
                                const int* __restrict__ src, const int* __restrict__ dst, int E,
                                int* __restrict__ sampi, float* __restrict__ sampw,
                                int* __restrict__ adj8) {
    int v = blockIdx.x * 256 + threadIdx.x;
    if (v >= V) return;
    float X = verts[3 * v + 0], Yy = verts[3 * v + 1], Z = verts[3 * v + 2];
    float cx = cam_c[0], cy = cam_c[1], fx = cam_f[0], fy = cam_f[1];
    const float tz = 0.8f;
    float pz = Z + tz;
    float px = (fx * X + cx * Z + tz * cx) / pz;
    float py = (fy * Yy + cy * Z + tz * cy) / pz;
    float is = (float)imgsz[0];
    const int Ss[3] = {56, 28, 14};
#pragma unroll
    for (int m = 0; m < 3; ++m) {
        int S = Ss[m];
        float dim = (float)S;
        float x = px * dim / is;
        float y = py * dim / is;
        float x1 = floorf(x), y1 = floorf(y);
        float x2 = x1 + 1.0f, y2 = y1 + 1.0f;
        float smax = (float)(S - 1);
        int xi1 = (int)fminf(fmaxf(x1, 0.0f), smax);
        int xi2 = (int)fminf(fmaxf(x2, 0.0f), smax);
        int yi1 = (int)fminf(fmaxf(y1, 0.0f), smax);
        int yi2 = (int)fminf(fmaxf(y2, 0.0f), smax);
        int b = v * 12 + m * 4;
        sampi[b + 0] = xi1 * S + yi1;
        sampi[b + 1] = xi1 * S + yi2;
        sampi[b + 2] = xi2 * S + yi1;
        sampi[b + 3] = xi2 * S + yi2;
        sampw[b + 0] = (x2 - x) * (y2 - y);
        sampw[b + 1] = (x2 - x) * (y - y1);
        sampw[b + 2] = (x - x1) * (y2 - y);
        sampw[b + 3] = (x - x1) * (y - y1);
    }
    // fixed-degree adjacency via two binary searches on sorted src
    int lo = 0, hi = E;
    while (lo < hi) { int m = (lo + hi) >> 1; if (src[m] < v) lo = m + 1; else hi = m; }
    int e0 = lo;
    hi = E;
    while (lo < hi) { int m = (lo + hi) >> 1; if (src[m] < v + 1) lo = m + 1; else hi = m; }
    int e1 = lo;
    int* ap = adj8 + (size_t)v * 8;
#pragma unroll
    for (int i = 0; i < 8; ++i) {
        int e = e0 + i;
        ap[i] = (e < e1) ? dst[e] : -1;
    }
}

// ---------------- MFMA bf16x3 GEMM (G precompute + shape GEMM) --------------
struct MArgs {
    const unsigned short *Ahi, *Alo; int lda;
    const unsigned short *Bhi, *Blo; int K;  // Bt row-major [N][K]
    float* Y;
    int sstr;
    int V;
};

template <int EPI>
__global__ __launch_bounds__(256) void mgemm(MArgs g) {
    __shared__ unsigned short As_hi[64][40], As_lo[64][40];
    __shared__ unsigned short Bs_hi[128][40], Bs_lo[128][40];
    int tid = threadIdx.x;
    int row0 = blockIdx.y * 64;
    int col0 = blockIdx.x * 128;
    int l = tid & 63, wid = tid >> 6;
    int wr = wid & 1, wc = wid >> 1;
    int lw = l & 15, gg = l >> 4;
    f32x4v acc[2][4];
#pragma unroll
    for (int i = 0; i < 2; ++i)
#pragma unroll
        for (int j = 0; j < 4; ++j) acc[i][j] = (f32x4v){0.f, 0.f, 0.f, 0.f};

    int arow = tid >> 2, akoff = (tid & 3) * 8;
    for (int k0 = 0; k0 < g.K; k0 += 32) {
        __syncthreads();
        {
            int grow = row0 + arow;
            uint4 zh = make_uint4(0, 0, 0, 0), zl = make_uint4(0, 0, 0, 0);
            if (grow < g.V) {
                zh = *(const uint4*)(g.Ahi + (size_t)grow * g.lda + k0 + akoff);
                zl = *(const uint4*)(g.Alo + (size_t)grow * g.lda + k0 + akoff);
            }
            *(uint4*)&As_hi[arow][akoff] = zh;
            *(uint4*)&As_lo[arow][akoff] = zl;
        }
#pragma unroll
        for (int it = 0; it < 2; ++it) {
            int q = tid + it * 256;
            int n = q >> 2, koff = (q & 3) * 8;
            *(uint4*)&Bs_hi[n][koff] = *(const uint4*)(g.Bhi + (size_t)(col0 + n) * g.K + k0 + koff);
            *(uint4*)&Bs_lo[n][koff] = *(const uint4*)(g.Blo + (size_t)(col0 + n) * g.K + k0 + koff);
        }
        __syncthreads();
        bf16x8v ah[2], al[2], bh[4], bl[4];
#pragma unroll
        for (int mt = 0; mt < 2; ++mt) {
            int r = wr * 32 + mt * 16 + lw;
            ah[mt] = *(const bf16x8v*)&As_hi[r][gg * 8];
            al[mt] = *(const bf16x8v*)&As_lo[r][gg * 8];
        }
#pragma unroll
        for (int nt = 0; nt < 4; ++nt) {
            int c = wc * 64 + nt * 16 + lw;
            bh[nt] = *(const bf16x8v*)&Bs_hi[c][gg * 8];
            bl[nt] = *(const bf16x8v*)&Bs_lo[c][gg * 8];
        }
#pragma unroll
        for (int mt = 0; mt < 2; ++mt)
#pragma unroll
            for (int nt = 0; nt < 4; ++nt) {
                acc[mt][nt] = __builtin_amdgcn_mfma_f32_16x16x32_bf16(ah[mt], bh[nt], acc[mt][nt], 0, 0, 0);
                acc[mt][nt] = __builtin_amdgcn_mfma_f32_16x16x32_bf16(ah[mt], bl[nt], acc[mt][nt], 0, 0, 0);
                acc[mt][nt] = __builtin_amdgcn_mfma_f32_16x16x32_bf16(al[mt], bh[nt], acc[mt][nt], 0, 0, 0);
            }
    }
#pragma unroll
    for (int mt = 0; mt < 2; ++mt)
#pragma unroll
        for (int nt = 0; nt < 4; ++nt) {
            int colg = wc * 64 + nt * 16 + lw;
#pragma unroll
            for (int r = 0; r < 4; ++r) {
                int rowg = row0 + wr * 32 + mt * 16 + gg * 4 + r;
                if (rowg >= g.V) continue;
                float v = acc[mt][nt][r];
                if (EPI == 3) {
                    g.Y[(size_t)rowg * 256 + col0 + colg] = v;
                } else {
                    int cg = col0 + colg;
                    g.Y[(size_t)(cg >> 8) * g.sstr + (size_t)rowg * 256 + (cg & 255)] = v;
                }
            }
        }
}

// ---------------- input perceptual gather (float4, 64 thr/vertex) -----------
__global__ void gather_kernel(const float* __restrict__ G, int sstr,
                              const int* __restrict__ sampi, const float* __restrict__ sampw,
                              float* __restrict__ Yb, int V, int stage,
                              const float* __restrict__ Win0, const float* __restrict__ Win1,
                              const float* __restrict__ shape) {
    int v = xcd_swz(blockIdx.x, gridDim.x) * 4 + (threadIdx.x >> 6);
    if (v >= V) return;
    int j = (threadIdx.x & 63) * 4;
    const float* Gs = G + (size_t)stage * sstr;
    int b = v * 12;
    float4 acc;
    if (stage == 0) acc = make_float4(0.f, 0.f, 0.f, 0.f);
    else acc = *(const float4*)(Yb + (size_t)v * 256 + j);
#pragma unroll
    for (int s = 0; s < 4; ++s) {
        float w = sampw[b + s];
        float4 f = *(const float4*)(Gs + (size_t)sampi[b + s] * 256 + j);
        acc.x += w * f.x; acc.y += w * f.y; acc.z += w * f.z; acc.w += w * f.w;
    }
#pragma unroll
    for (int s = 0; s < 4; ++s) {
        float w = sampw[b + 4 + s];
        float4 f = *(const float4*)(Gs + (size_t)(3136 + sampi[b + 4 + s]) * 256 + j);
        acc.x += w * f.x; acc.y += w * f.y; acc.z += w * f.z; acc.w += w * f.w;
    }
#pragma unroll
    for (int s = 0; s < 4; ++s) {
        float w = sampw[b + 8 + s];
        float4 f = *(const float4*)(Gs + (size_t)(3920 + sampi[b + 8 + s]) * 256 + j);
        acc.x += w * f.x; acc.y += w * f.y; acc.z += w * f.z; acc.w += w * f.w;
    }
    if (stage == 0) {
#pragma unroll
        for (int k = 0; k < 3; ++k) {
            float w = shape[v * 3 + k];
            const float* wr = (j < 128) ? Win0 + (size_t)(1280 + k) * 128 + j
                                        : Win1 + (size_t)(1280 + k) * 128 + (j - 128);
            float4 wv = *(const float4*)wr;
            acc.x += w * wv.x; acc.y += w * wv.y; acc.z += w * wv.z; acc.w += w * wv.w;
        }
    }
    *(float4*)(Yb + (size_t)v * 256 + j) = acc;
}

// ---------------- input-layer combine (float4, 32 thr/vertex) ---------------
__global__ __launch_bounds__(256) void combine_in(
    const float* __restrict__ Y, const float* __restrict__ bias,
    const int* __restrict__ adj8,
    float* __restrict__ hout, int V) {
    int v = xcd_swz(blockIdx.x, gridDim.x) * 8 + (threadIdx.x >> 5);
    if (v >= V) return;
    int d = (threadIdx.x & 31) * 4;
    float4 val = *(const float4*)(Y + (size_t)v * 256 + d);
    float4 b4 = *(const float4*)(bias + d);
    val.x += b4.x; val.y += b4.y; val.z += b4.z; val.w += b4.w;
    const int* ap = adj8 + (size_t)v * 8;
    int n[6];
#pragma unroll
    for (int i = 0; i < 6; ++i) n[i] = ap[i];
#pragma unroll
    for (int i = 0; i < 6; ++i) {
        if (n[i] >= 0) {
            float4 f = *(const float4*)(Y + (size_t)n[i] * 256 + 128 + d);
            val.x += f.x; val.y += f.y; val.z += f.z; val.w += f.w;
        }
    }
    val.x = fmaxf(val.x, 0.f); val.y = fmaxf(val.y, 0.f);
    val.z = fmaxf(val.z, 0.f); val.w = fmaxf(val.w, 0.f);
    *(float4*)(hout + (size_t)v * 128 + d) = val;
}

// ---------------- fused resnet layer: K-split wave specialization -----------
// Pair of waves per 16-row tile: role 0 = own half (K 0..127, streaming),
// role 1 = agg half (K 128..255, 6-neighbor gather). Partials combined in LDS,
// single barrier. PAIRS pairs per block (PAIRS*16 rows, PAIRS*128 threads).
struct LArgs {
    const float* h;                                   // [V][128] f32
    const unsigned short* Bp;                         // packed [64][2][512]
    const int* adj8;
    const float* bias;
    float* hnext;
    int V;
};

template <int PAIRS>
__global__ __launch_bounds__(PAIRS * 128) void lay_kernel(LArgs g) {
    __shared__ float psum[PAIRS][16][132];
    int tid = threadIdx.x;
    int wid = tid >> 6, l = tid & 63;
    int pair = wid >> 1, role = wid & 1;
    int rowbase = xcd_swz(blockIdx.x, gridDim.x) * (PAIRS * 16) + pair * 16;
    int lrow = l & 15, lks = l >> 4;
    int grow = rowbase + lrow;
    bool act = grow < g.V;

    f32x4v acc[8];
#pragma unroll
    for (int nt = 0; nt < 8; ++nt) acc[nt] = (f32x4v){0.f, 0.f, 0.f, 0.f};

    if (role == 0) {
        // ---- own half: K 0..127, coalesced row stream ----
        const float* hp = g.h + (size_t)grow * 128;
#pragma unroll
        for (int ks = 0; ks < 4; ++ks) {
            int kb = ks * 32 + lks * 8;
            float a[8];
            if (act) {
                float4 f0 = *(const float4*)(hp + kb);
                float4 f1 = *(const float4*)(hp + kb + 4);
                a[0] = f0.x; a[1] = f0.y; a[2] = f0.z; a[3] = f0.w;
                a[4] = f1.x; a[5] = f1.y; a[6] = f1.z; a[7] = f1.w;
            } else {
#pragma unroll
                for (int i = 0; i < 8; ++i) a[i] = 0.f;
            }
            unsigned short hh[8], ll[8];
#pragma unroll
            for (int i = 0; i < 8; ++i) f2hl(a[i], hh[i], ll[i]);
            bf16x8v ah = *(const bf16x8v*)hh;
            bf16x8v al = *(const bf16x8v*)ll;
#pragma unroll
            for (int nt = 0; nt < 8; ++nt) {
                const unsigned short* p = g.Bp + (size_t)(ks * 8 + nt) * 1024 + l * 8;
                bf16x8v bh = *(const bf16x8v*)p;
                bf16x8v bl = *(const bf16x8v*)(p + 512);
                acc[nt] = __builtin_amdgcn_mfma_f32_16x16x32_bf16(ah, bh, acc[nt], 0, 0, 0);
                acc[nt] = __builtin_amdgcn_mfma_f32_16x16x32_bf16(ah, bl, acc[nt], 0, 0, 0);
                acc[nt] = __builtin_amdgcn_mfma_f32_16x16x32_bf16(al, bh, acc[nt], 0, 0, 0);
            }
        }
    } else {
        // ---- agg half: K 128..255, 6 independent neighbor-row gathers ----
        int n[6];
        if (act) {
            const int* ap = g.adj8 + (size_t)grow * 8;
#pragma unroll
            for (int i = 0; i < 6; ++i) n[i] = ap[i];
        } else {
#pragma unroll
            for (int i = 0; i < 6; ++i) n[i] = -1;
        }
#pragma unroll
        for (int ks = 0; ks < 4; ++ks) {
            int ko = ks * 32 + lks * 8;
            float a[8];
#pragma unroll
            for (int i = 0; i < 8; ++i) a[i] = 0.f;
#pragma unroll
            for (int i = 0; i < 6; ++i) {
                if (n[i] >= 0) {
                    const float* hp = g.h + (size_t)n[i] * 128 + ko;
                    float4 f0 = *(const float4*)hp;
                    float4 f1 = *(const float4*)(hp + 4);
                    a[0] += f0.x; a[1] += f0.y; a[2] += f0.z; a[3] += f0.w;
                    a[4] += f1.x; a[5] += f1.y; a[6] += f1.z; a[7] += f1.w;
                }
            }
            unsigned short hh[8], ll[8];
#pragma unroll
            for (int i = 0; i < 8; ++i) f2hl(a[i], hh[i], ll[i]);
            bf16x8v ah = *(const bf16x8v*)hh;
            bf16x8v al = *(const bf16x8v*)ll;
#pragma unroll
            for (int nt = 0; nt < 8; ++nt) {
                const unsigned short* p = g.Bp + (size_t)((ks + 4) * 8 + nt) * 1024 + l * 8;
                bf16x8v bh = *(const bf16x8v*)p;
                bf16x8v bl = *(const bf16x8v*)(p + 512);
                acc[nt] = __builtin_amdgcn_mfma_f32_16x16x32_bf16(ah, bh, acc[nt], 0, 0, 0);
                acc[nt] = __builtin_amdgcn_mfma_f32_16x16x32_bf16(ah, bl, acc[nt], 0, 0, 0);
                acc[nt] = __builtin_amdgcn_mfma_f32_16x16x32_bf16(al, bh, acc[nt], 0, 0, 0);
            }
        }
        // stash agg partials: C[row=lks*4+r][col=nt*16+lrow]
#pragma unroll
        for (int nt = 0; nt < 8; ++nt)
#pragma unroll
            for (int r = 0; r < 4; ++r)
                psum[pair][lks * 4 + r][nt * 16 + lrow] = acc[nt][r];
    }
    __syncthreads();
    if (role == 0) {
        // ---- epilogue: hnext = relu(own + agg + bias) + h ----
#pragma unroll
        for (int nt = 0; nt < 8; ++nt) {
            int colg = nt * 16 + lrow;
            float bv = g.bias[colg];
#pragma unroll
            for (int r = 0; r < 4; ++r) {
                int rowg = rowbase + lks * 4 + r;
                if (rowg < g.V) {
                    float v = acc[nt][r] + psum[pair][lks * 4 + r][colg] + bv;
                    v = fmaxf(v, 0.0f);
                    v += g.h[(size_t)rowg * 128 + colg];
                    g.hnext[(size_t)rowg * 128 + colg] = v;
                }
            }
        }
    }
}

// ---------------- coord head ------------------------------------------------
__global__ void coordgemm_kernel(const float* __restrict__ h,
                                 const float* __restrict__ Wc0, const float* __restrict__ Wc1,
                                 int V, float* __restrict__ Yc) {
    int idx = blockIdx.x * 256 + threadIdx.x;
    if (idx >= V * 6) return;
    int v = idx / 6, j = idx % 6;
    const float* W = (j < 3) ? Wc0 : Wc1;
    int jj = (j < 3) ? j : j - 3;
    const float* hp = h + (size_t)v * 128;
    float acc = 0.0f;
#pragma unroll
    for (int k = 0; k < 32; ++k) {
        float4 f = *(const float4*)(hp + k * 4);
        acc += f.x * W[(k * 4 + 0) * 3 + jj];
        acc += f.y * W[(k * 4 + 1) * 3 + jj];
        acc += f.z * W[(k * 4 + 2) * 3 + jj];
        acc += f.w * W[(k * 4 + 3) * 3 + jj];
    }
    Yc[idx] = acc;
}

__global__ void coordcombine_kernel(const float* __restrict__ Yc, const float* __restrict__ bc,
                                    const int* __restrict__ adj8,
                                    int V, float* __restrict__ out) {
    int idx = blockIdx.x * 256 + threadIdx.x;
    if (idx >= V * 3) return;
    int v = idx / 3, j = idx % 3;
    float val = Yc[(size_t)v * 6 + j] + bc[j];
    const int* ap = adj8 + (size_t)v * 8;
    int n[6];
#pragma unroll
    for (int i = 0; i < 6; ++i) n[i] = ap[i];
#pragma unroll
    for (int i = 0; i < 6; ++i)
        if (n[i] >= 0) val += Yc[(size_t)n[i] * 6 + 3 + j];
    out[(size_t)v * 3 + j] = val;
}

// ---------------- unpool: verts midpoints + featpack hi/lo ------------------
__global__ void unpool_kernel(float* __restrict__ verts, const float* __restrict__ h,
                              const int* __restrict__ mid, int V, int Nm,
                              unsigned short* __restrict__ fphi, unsigned short* __restrict__ fplo) {
    int r = blockIdx.x;
    int t = threadIdx.x;  // 128
    if (r < V) {
        float v = h[(size_t)r * 128 + t];
        unsigned short hi, lo;
        f2hl(v, hi, lo);
        fphi[(size_t)r * 128 + t] = hi;
        fplo[(size_t)r * 128 + t] = lo;
    } else {
        int i = r - V;
        int a = mid[2 * i], b = mid[2 * i + 1];
        float v = 0.5f * (h[(size_t)a * 128 + t] + h[(size_t)b * 128 + t]);
        unsigned short hi, lo;
        f2hl(v, hi, lo);
        fphi[(size_t)r * 128 + t] = hi;
        fplo[(size_t)r * 128 + t] = lo;
        if (t < 3)
            verts[(size_t)r * 3 + t] = 0.5f * (verts[(size_t)a * 3 + t] + verts[(size_t)b * 3 + t]);
    }
}

// ---------------------------------------------------------------------------
extern "C" void kernel_launch(void* const* d_in, const int* in_sizes, int n_in,
                              void* d_out, int out_size, void* d_ws, size_t ws_size,
                              hipStream_t stream) {
    const float* f3 = (const float*)d_in[0];
    const float* f4 = (const float*)d_in[1];
    const float* f5 = (const float*)d_in[2];
    const float* verts0 = (const float*)d_in[3];
    const float* cam_c = (const float*)d_in[4];
    const float* cam_f = (const float*)d_in[5];
    const int* imgsz = (const int*)d_in[38];

    int V0 = in_sizes[3] / 3;
    int E[3] = {in_sizes[33] / 2, in_sizes[34] / 2, in_sizes[35] / 2};
    int Nm0 = in_sizes[36] / 2, Nm1 = in_sizes[37] / 2;
    int V1 = V0 + Nm0, V2 = V1 + Nm1;
    int Vs[3] = {V0, V1, V2};
    const int NPIXT = 3136 + 784 + 196;  // 4116
    const int GS = NPIXT * 256;          // per-stage G stride (floats)

    // ---- workspace (byte allocator, 256B aligned) ----
    char* wsp = (char*)d_ws;
    auto alloc = [&](size_t bytes) -> void* {
        void* p = (void*)wsp;
        wsp += (bytes + 255) & ~(size_t)255;
        return p;
    };
    unsigned short* ft0h = (unsigned short*)alloc((size_t)3136 * 256 * 2);
    unsigned short* ft0l = (unsigned short*)alloc((size_t)3136 * 256 * 2);
    unsigned short* ft1h = (unsigned short*)alloc((size_t)784 * 512 * 2);
    unsigned short* ft1l = (unsigned short*)alloc((size_t)784 * 512 * 2);
    unsigned short* ft2h = (unsigned short*)alloc((size_t)196 * 512 * 2);
    unsigned short* ft2l = (unsigned short*)alloc((size_t)196 * 512 * 2);
    unsigned short* Bg0h = (unsigned short*)alloc((size_t)768 * 256 * 2);
    unsigned short* Bg0l = (unsigned short*)alloc((size_t)768 * 256 * 2);
    unsigned short* Bg1h = (unsigned short*)alloc((size_t)768 * 512 * 2);
    unsigned short* Bg1l = (unsigned short*)alloc((size_t)768 * 512 * 2);
    unsigned short* Bg2h = (unsigned short*)alloc((size_t)768 * 512 * 2);
    unsigned short* Bg2l = (unsigned short*)alloc((size_t)768 * 512 * 2);
    float* Gbuf = (float*)alloc((size_t)3 * GS * 4);
    unsigned short* BtLp[3];
    for (int s = 0; s < 3; ++s)
        BtLp[s] = (unsigned short*)alloc((size_t)12 * 65536 * 2);  // fragment-packed hi+lo
    unsigned short* BtShi[2];
    unsigned short* BtSlo[2];
    for (int s = 0; s < 2; ++s) {
        BtShi[s] = (unsigned short*)alloc((size_t)256 * 128 * 2);
        BtSlo[s] = (unsigned short*)alloc((size_t)256 * 128 * 2);
    }
    float* Ybuf = (float*)alloc((size_t)V2 * 256 * 4);
    float* hA = (float*)alloc((size_t)V2 * 128 * 4);
    float* hB = (float*)alloc((size_t)V2 * 128 * 4);
    unsigned short* FPhi = (unsigned short*)alloc((size_t)V2 * 128 * 2);
    unsigned short* FPlo = (unsigned short*)alloc((size_t)V2 * 128 * 2);
    float* vertsbuf = (float*)alloc((size_t)V2 * 3 * 4);
    float* Yc = (float*)alloc((size_t)V2 * 6 * 4);
    int* sampi = (int*)alloc((size_t)V2 * 12 * 4);
    float* sampw = (float*)alloc((size_t)V2 * 12 * 4);
    int* adj8 = (int*)alloc((size_t)V2 * 8 * 4);

    // ---- feature map transpose + hi/lo split ----
    transpose_hl<<<DIV_UP(256 * 56 * 56, 256), 256, 0, stream>>>(f3, ft0h, ft0l, 256, 56 * 56);
    transpose_hl<<<DIV_UP(512 * 28 * 28, 256), 256, 0, stream>>>(f4, ft1h, ft1l, 512, 28 * 28);
    transpose_hl<<<DIV_UP(512 * 14 * 14, 256), 256, 0, stream>>>(f5, ft2h, ft2l, 512, 14 * 14);

    // ---- single fused weight pack ----
    {
        PackArgs p;
        for (int s = 0; s < 3; ++s) {
            p.Win0[s] = (const float*)d_in[6 + s * 9 + 0];
            p.Win1[s] = (const float*)d_in[6 + s * 9 + 1];
            p.W0L[s] = (const float*)d_in[6 + s * 9 + 3];
            p.W1L[s] = (const float*)d_in[6 + s * 9 + 4];
            p.BtLp[s] = BtLp[s];
        }
        p.BtShi[0] = BtShi[0]; p.BtSlo[0] = BtSlo[0];
        p.BtShi[1] = BtShi[1]; p.BtSlo[1] = BtSlo[1];
        p.Bgh[0] = Bg0h; p.Bgl[0] = Bg0l;
        p.Bgh[1] = Bg1h; p.Bgl[1] = Bg1l;
        p.Bgh[2] = Bg2h; p.Bgl[2] = Bg2l;
        int total = 3 * 12 * 32768 + 2 * 256 * 128 + 768 * 256 + 2 * 768 * 512;
        pack_all<<<DIV_UP(total, 256), 256, 0, stream>>>(p);
    }

    // ---- G precompute (MFMA): G[s][pix][256] = ft_m @ W-slice ----
    {
        MArgs m = {};
        m.sstr = GS;
        m.Ahi = ft0h; m.Alo = ft0l; m.lda = 256;
        m.Bhi = Bg0h; m.Blo = Bg0l; m.K = 256;
        m.Y = Gbuf; m.V = 3136;
        dim3 g0(6, DIV_UP(3136, 64));
        mgemm<2><<<g0, 256, 0, stream>>>(m);
        m.Ahi = ft1h; m.Alo = ft1l; m.lda = 512;
        m.Bhi = Bg1h; m.Blo = Bg1l; m.K = 512;
        m.Y = Gbuf + (size_t)3136 * 256; m.V = 784;
        dim3 g1(6, DIV_UP(784, 64));
        mgemm<2><<<g1, 256, 0, stream>>>(m);
        m.Ahi = ft2h; m.Alo = ft2l; m.lda = 512;
        m.Bhi = Bg2h; m.Blo = Bg2l; m.K = 512;
        m.Y = Gbuf + (size_t)3920 * 256; m.V = 196;
        dim3 g2(6, DIV_UP(196, 64));
        mgemm<2><<<g2, 256, 0, stream>>>(m);
    }

    for (int si = 0; si < 3; ++si) {
        const float* Win0 = (const float*)d_in[6 + si * 9 + 0];
        const float* Win1 = (const float*)d_in[6 + si * 9 + 1];
        const float* bin = (const float*)d_in[6 + si * 9 + 2];
        const float* bs = (const float*)d_in[6 + si * 9 + 5];
        const float* Wc0 = (const float*)d_in[6 + si * 9 + 6];
        const float* Wc1 = (const float*)d_in[6 + si * 9 + 7];
        const float* bc = (const float*)d_in[6 + si * 9 + 8];
        const int* edges = (const int*)d_in[33 + si];
        int Ecur = E[si];
        const int* esrc = edges;
        const int* edst = edges + Ecur;
        int V = Vs[si];
        const float* vertsin = (si == 0) ? verts0 : vertsbuf;

        desc_adj_kernel<<<DIV_UP(V, 256), 256, 0, stream>>>(vertsin, cam_c, cam_f, imgsz, V,
                                                            esrc, edst, Ecur, sampi, sampw, adj8);
        // shape GEMM first (pure store), then gather adds perceptual part
        if (si > 0) {
            MArgs m = {};
            m.Ahi = FPhi; m.Alo = FPlo; m.lda = 128;
            m.Bhi = BtShi[si - 1]; m.Blo = BtSlo[si - 1]; m.K = 128;
            m.Y = Ybuf; m.V = V;
            dim3 grid(2, DIV_UP(V, 64));
            mgemm<3><<<grid, 256, 0, stream>>>(m);
        }
        gather_kernel<<<DIV_UP(V, 4), 256, 0, stream>>>(Gbuf, GS, sampi, sampw, Ybuf, V, si,
                                                        Win0, Win1, (si == 0) ? verts0 : nullptr);
        combine_in<<<DIV_UP(V, 8), 256, 0, stream>>>(Ybuf, bin, adj8, hA, V);

        float* hcur = hA;
        float* hnext = hB;
        for (int ll = 0; ll < 12; ++ll) {
            LArgs a = {};
            a.h = hcur;
            a.Bp = BtLp[si] + (size_t)ll * 65536;
            a.adj8 = adj8;
            a.bias = bs + (size_t)ll * 128;
            a.hnext = hnext;
            a.V = V;
            if (si == 2) {
                lay_kernel<2><<<DIV_UP(V, 32), 256, 0, stream>>>(a);
            } else {
                lay_kernel<1><<<DIV_UP(V, 16), 128, 0, stream>>>(a);
            }
            float* t = hcur; hcur = hnext; hnext = t;
        }

        coordgemm_kernel<<<DIV_UP(V * 6, 256), 256, 0, stream>>>(hcur, Wc0, Wc1, V, Yc);
        float* ctarget = (si == 2) ? (float*)d_out : vertsbuf;
        coordcombine_kernel<<<DIV_UP(V * 3, 256), 256, 0, stream>>>(Yc, bc, adj8, V, ctarget);
        if (si < 2) {
            const int* mid = (const int*)d_in[36 + si];
            int Nm = (si == 0) ? Nm0 : Nm1;
            unpool_kernel<<<V + Nm, 128, 0, stream>>>(vertsbuf, hcur, mid, V, Nm, FPhi, FPlo);
        }
    }
}

// Round 9
// 1384.732 us; speedup vs baseline: 1.5389x; 1.0179x over previous
//
#include <hip/hip_runtime.h>
#include <hip/hip_bf16.h>
#include <cstddef>
#include <cstdint>

#define DIV_UP(a, b) (((a) + (b) - 1) / (b))

typedef __attribute__((ext_vector_type(8))) short bf16x8v;
typedef __attribute__((ext_vector_type(4))) float f32x4v;

__device__ __forceinline__ unsigned short bf16_rn(float v) {
    unsigned int u = __float_as_uint(v);
    unsigned int r = (u + 0x7FFFu + ((u >> 16) & 1u)) >> 16;
    return (unsigned short)r;
}
__device__ __forceinline__ float bf16_f(unsigned short h) {
    return __uint_as_float(((unsigned int)h) << 16);
}
__device__ __forceinline__ void f2hl(float v, unsigned short& hi, unsigned short& lo) {
    hi = bf16_rn(v);
    float r = v - bf16_f(hi);
    lo = bf16_rn(r);
}
__device__ __forceinline__ int xcd_swz(int orig, int nwg) {
    int q = nwg >> 3, r = nwg & 7;
    int xcd = orig & 7, idx = orig >> 3;
    return (xcd < r ? xcd * (q + 1) : r * (q + 1) + (xcd - r) * q) + idx;
}

// ---------------- transpose (C,H,W) f32 -> (H*W, C) bf16 hi/lo --------------
__global__ void transpose_hl(const float* __restrict__ in, unsigned short* __restrict__ ohi,
                             unsigned short* __restrict__ olo, int C, int HW) {
    int idx = blockIdx.x * 256 + threadIdx.x;
    if (idx >= C * HW) return;
    int c = idx % C;
    int p = idx / C;
    float v = in[(size_t)c * HW + p];
    unsigned short hi, lo;
    f2hl(v, hi, lo);
    ohi[(size_t)p * C + c] = hi;
    olo[(size_t)p * C + c] = lo;
}

// ---------------- single fused weight-pack kernel ---------------------------
// Layer weights packed in MFMA-fragment order:
//   BtLp[st][layer][ks(8)][nt(8)][hl(2)][lane(64)][i(8)]
// fragment value = Bt[n = nt*16+(lane&15)][k = ks*32+(lane>>4)*8+i]
struct PackArgs {
    const float* Win0[3]; const float* Win1[3];   // [1408|1283][128]
    const float* W0L[3];  const float* W1L[3];    // [12][128][128]
    unsigned short* BtLp[3];                      // [12][64][2][512]
    unsigned short *BtShi[2], *BtSlo[2];          // stages 1,2: [256][128]
    unsigned short *Bgh[3], *Bgl[3];              // [768][C] C=256,512,512
};

__global__ void pack_all(PackArgs p) {
    const int LAY1 = 12 * 32768;               // 393216 per stage
    const int LAYT = 3 * LAY1;                 // 1179648
    const int SH1 = 256 * 128;                 // 32768 per stage
    const int SHT = 2 * SH1;
    const int GB0 = 768 * 256, GB1 = 768 * 512;
    int idx = blockIdx.x * 256 + threadIdx.x;
    if (idx < LAYT) {
        int st = idx / LAY1, r = idx % LAY1;
        int layer = r >> 15, q = r & 32767;
        int ks = q >> 12, nt = (q >> 9) & 7, lane = (q >> 3) & 63, i = q & 7;
        int n = nt * 16 + (lane & 15);
        int k = ks * 32 + ((lane >> 4) << 3) + i;
        float v = (k < 128) ? p.W0L[st][(size_t)layer * 16384 + k * 128 + n]
                            : p.W1L[st][(size_t)layer * 16384 + (k - 128) * 128 + n];
        unsigned short hi, lo;
        f2hl(v, hi, lo);
        size_t base = ((size_t)layer * 64 + ks * 8 + nt) * 1024 + lane * 8 + i;
        p.BtLp[st][base] = hi;
        p.BtLp[st][base + 512] = lo;
        return;
    }
    float v;
    unsigned short* dh;
    unsigned short* dl;
    size_t o;
    if (idx < LAYT + SHT) {
        int q = idx - LAYT;
        int st = q / SH1, rr = q % SH1;
        int n = rr >> 7, k = rr & 127;
        const float* w0 = p.Win0[st + 1];
        const float* w1 = p.Win1[st + 1];
        v = (n < 128) ? w0[(size_t)(1280 + k) * 128 + n]
                      : w1[(size_t)(1280 + k) * 128 + (n - 128)];
        dh = p.BtShi[st]; dl = p.BtSlo[st]; o = rr;
    } else {
        int q = idx - LAYT - SHT;
        int m, C, base;
        if (q < GB0) { m = 0; C = 256; base = 0; }
        else if (q < GB0 + GB1) { m = 1; C = 512; base = 256; q -= GB0; }
        else if (q < GB0 + 2 * GB1) { m = 2; C = 512; base = 768; q -= GB0 + GB1; }
        else return;
        int n = q / C, k = q % C;
        int s = n >> 8, j = n & 255;
        v = (j < 128) ? p.Win0[s][(size_t)(base + k) * 128 + j]
                      : p.Win1[s][(size_t)(base + k) * 128 + (j - 128)];
        dh = p.Bgh[m]; dl = p.Bgl[m]; o = q;
    }
    unsigned short hi, lo;
    f2hl(v, hi, lo);
    dh[o] = hi;
    dl[o] = lo;
}

// -------- per-vertex projection/bilerp descriptors + fixed-degree adj -------
__global__ void desc_adj_kernel(const float* __restrict__ verts,
                                const float* __restrict__ cam_c, const float* __restrict__ cam_f,
                                const int* __restrict__ imgsz, int V,
                                const int* __restrict__ src, const int* __restrict__ dst, int E,
                                int* __restrict__ sampi, float* __restrict__ sampw,
                                int* __restrict__ adj8) {
    int v = blockIdx.x * 256 + threadIdx.x;
    if (v >= V) return;
    float X = verts[3 * v + 0], Yy = verts[3 * v + 1], Z = verts[3 * v + 2];
    float cx = cam_c[0], cy = cam_c[1], fx = cam_f[0], fy = cam_f[1];
    const float tz = 0.8f;
    float pz = Z + tz;
    float px = (fx * X + cx * Z + tz * cx) / pz;
    float py = (fy * Yy + cy * Z + tz * cy) / pz;
    float is = (float)imgsz[0];
    const int Ss[3] = {56, 28, 14};
#pragma unroll
    for (int m = 0; m < 3; ++m) {
        int S = Ss[m];
        float dim = (float)S;
        float x = px * dim / is;
        float y = py * dim / is;
        float x1 = floorf(x), y1 = floorf(y);
        float x2 = x1 + 1.0f, y2 = y1 + 1.0f;
        float smax = (float)(S - 1);
        int xi1 = (int)fminf(fmaxf(x1, 0.0f), smax);
        int xi2 = (int)fminf(fmaxf(x2, 0.0f), smax);
        int yi1 = (int)fminf(fmaxf(y1, 0.0f), smax);
        int yi2 = (int)fminf(fmaxf(y2, 0.0f), smax);
        int b = v * 12 + m * 4;
        sampi[b + 0] = xi1 * S + yi1;
        sampi[b + 1] = xi1 * S + yi2;
        sampi[b + 2] = xi2 * S + yi1;
        sampi[b + 3] = xi2 * S + yi2;
        sampw[b + 0] = (x2 - x) * (y2 - y);
        sampw[b + 1] = (x2 - x) * (y - y1);
        sampw[b + 2] = (x - x1) * (y2 - y);
        sampw[b + 3] = (x - x1) * (y - y1);
    }
    // fixed-degree adjacency via two binary searches on sorted src
    int lo = 0, hi = E;
    while (lo < hi) { int m = (lo + hi) >> 1; if (src[m] < v) lo = m + 1; else hi = m; }
    int e0 = lo;
    hi = E;
    while (lo < hi) { int m = (lo + hi) >> 1; if (src[m] < v + 1) lo = m + 1; else hi = m; }
    int e1 = lo;
    int* ap = adj8 + (size_t)v * 8;
#pragma unroll
    for (int i = 0; i < 8; ++i) {
        int e = e0 + i;
        ap[i] = (e < e1) ? dst[e] : -1;
    }
}

// ---------------- MFMA bf16x3 GEMM (G precompute + shape GEMM) --------------
struct MArgs {
    const unsigned short *Ahi, *Alo; int lda;
    const unsigned short *Bhi, *Blo; int K;  // Bt row-major [N][K]
    float* Y;
    int sstr;
    int V;
};

template <int EPI>
__global__ __launch_bounds__(256) void mgemm(MArgs g) {
    __shared__ unsigned short As_hi[64][40], As_lo[64][40];
    __shared__ unsigned short Bs_hi[128][40], Bs_lo[128][40];
    int tid = threadIdx.x;
    int row0 = blockIdx.y * 64;
    int col0 = blockIdx.x * 128;
    int l = tid & 63, wid = tid >> 6;
    int wr = wid & 1, wc = wid >> 1;
    int lw = l & 15, gg = l >> 4;
    f32x4v acc[2][4];
#pragma unroll
    for (int i = 0; i < 2; ++i)
#pragma unroll
        for (int j = 0; j < 4; ++j) acc[i][j] = (f32x4v){0.f, 0.f, 0.f, 0.f};

    int arow = tid >> 2, akoff = (tid & 3) * 8;
    for (int k0 = 0; k0 < g.K; k0 += 32) {
        __syncthreads();
        {
            int grow = row0 + arow;
            uint4 zh = make_uint4(0, 0, 0, 0), zl = make_uint4(0, 0, 0, 0);
            if (grow < g.V) {
                zh = *(const uint4*)(g.Ahi + (size_t)grow * g.lda + k0 + akoff);
                zl = *(const uint4*)(g.Alo + (size_t)grow * g.lda + k0 + akoff);
            }
            *(uint4*)&As_hi[arow][akoff] = zh;
            *(uint4*)&As_lo[arow][akoff] = zl;
        }
#pragma unroll
        for (int it = 0; it < 2; ++it) {
            int q = tid + it * 256;
            int n = q >> 2, koff = (q & 3) * 8;
            *(uint4*)&Bs_hi[n][koff] = *(const uint4*)(g.Bhi + (size_t)(col0 + n) * g.K + k0 + koff);
            *(uint4*)&Bs_lo[n][koff] = *(const uint4*)(g.Blo + (size_t)(col0 + n) * g.K + k0 + koff);
        }
        __syncthreads();
        bf16x8v ah[2], al[2], bh[4], bl[4];
#pragma unroll
        for (int mt = 0; mt < 2; ++mt) {
            int r = wr * 32 + mt * 16 + lw;
            ah[mt] = *(const bf16x8v*)&As_hi[r][gg * 8];
            al[mt] = *(const bf16x8v*)&As_lo[r][gg * 8];
        }
#pragma unroll
        for (int nt = 0; nt < 4; ++nt) {
            int c = wc * 64 + nt * 16 + lw;
            bh[nt] = *(const bf16x8v*)&Bs_hi[c][gg * 8];
            bl[nt] = *(const bf16x8v*)&Bs_lo[c][gg * 8];
        }
#pragma unroll
        for (int mt = 0; mt < 2; ++mt)
#pragma unroll
            for (int nt = 0; nt < 4; ++nt) {
                acc[mt][nt] = __builtin_amdgcn_mfma_f32_16x16x32_bf16(ah[mt], bh[nt], acc[mt][nt], 0, 0, 0);
                acc[mt][nt] = __builtin_amdgcn_mfma_f32_16x16x32_bf16(ah[mt], bl[nt], acc[mt][nt], 0, 0, 0);
                acc[mt][nt] = __builtin_amdgcn_mfma_f32_16x16x32_bf16(al[mt], bh[nt], acc[mt][nt], 0, 0, 0);
            }
    }
#pragma unroll
    for (int mt = 0; mt < 2; ++mt)
#pragma unroll
        for (int nt = 0; nt < 4; ++nt) {
            int colg = wc * 64 + nt * 16 + lw;
#pragma unroll
            for (int r = 0; r < 4; ++r) {
                int rowg = row0 + wr * 32 + mt * 16 + gg * 4 + r;
                if (rowg >= g.V) continue;
                float v = acc[mt][nt][r];
                if (EPI == 3) {
                    g.Y[(size_t)rowg * 256 + col0 + colg] = v;
                } else {
                    int cg = col0 + colg;
                    g.Y[(size_t)(cg >> 8) * g.sstr + (size_t)rowg * 256 + (cg & 255)] = v;
                }
            }
        }
}

// ---------------- input perceptual gather (float4, 64 thr/vertex) -----------
__global__ void gather_kernel(const float* __restrict__ G, int sstr,
                              const int* __restrict__ sampi, const float* __restrict__ sampw,
                              float* __restrict__ Yb, int V, int stage,
                              const float* __restrict__ Win0, const float* __restrict__ Win1,
                              const float* __restrict__ shape) {
    int v = xcd_swz(blockIdx.x, gridDim.x) * 4 + (threadIdx.x >> 6);
    if (v >= V) return;
    int j = (threadIdx.x & 63) * 4;
    const float* Gs = G + (size_t)stage * sstr;
    int b = v * 12;
    float4 acc;
    if (stage == 0) acc = make_float4(0.f, 0.f, 0.f, 0.f);
    else acc = *(const float4*)(Yb + (size_t)v * 256 + j);
#pragma unroll
    for (int s = 0; s < 4; ++s) {
        float w = sampw[b + s];
        float4 f = *(const float4*)(Gs + (size_t)sampi[b + s] * 256 + j);
        acc.x += w * f.x; acc.y += w * f.y; acc.z += w * f.z; acc.w += w * f.w;
    }
#pragma unroll
    for (int s = 0; s < 4; ++s) {
        float w = sampw[b + 4 + s];
        float4 f = *(const float4*)(Gs + (size_t)(3136 + sampi[b + 4 + s]) * 256 + j);
        acc.x += w * f.x; acc.y += w * f.y; acc.z += w * f.z; acc.w += w * f.w;
    }
#pragma unroll
    for (int s = 0; s < 4; ++s) {
        float w = sampw[b + 8 + s];
        float4 f = *(const float4*)(Gs + (size_t)(3920 + sampi[b + 8 + s]) * 256 + j);
        acc.x += w * f.x; acc.y += w * f.y; acc.z += w * f.z; acc.w += w * f.w;
    }
    if (stage == 0) {
#pragma unroll
        for (int k = 0; k < 3; ++k) {
            float w = shape[v * 3 + k];
            const float* wr = (j < 128) ? Win0 + (size_t)(1280 + k) * 128 + j
                                        : Win1 + (size_t)(1280 + k) * 128 + (j - 128);
            float4 wv = *(const float4*)wr;
            acc.x += w * wv.x; acc.y += w * wv.y; acc.z += w * wv.z; acc.w += w * wv.w;
        }
    }
    *(float4*)(Yb + (size_t)v * 256 + j) = acc;
}

// ---------------- input-layer combine (float4, 32 thr/vertex) ---------------
__global__ __launch_bounds__(256) void combine_in(
    const float* __restrict__ Y, const float* __restrict__ bias,
    const int* __restrict__ adj8,
    float* __restrict__ hout, int V) {
    int v = xcd_swz(blockIdx.x, gridDim.x) * 8 + (threadIdx.x >> 5);
    if (v >= V) return;
    int d = (threadIdx.x & 31) * 4;
    float4 val = *(const float4*)(Y + (size_t)v * 256 + d);
    float4 b4 = *(const float4*)(bias + d);
    val.x += b4.x; val.y += b4.y; val.z += b4.z; val.w += b4.w;
    const int* ap = adj8 + (size_t)v * 8;
    int n[6];
#pragma unroll
    for (int i = 0; i < 6; ++i) n[i] = ap[i];
#pragma unroll
    for (int i = 0; i < 6; ++i) {
        if (n[i] >= 0) {
            float4 f = *(const float4*)(Y + (size_t)n[i] * 256 + 128 + d);
            val.x += f.x; val.y += f.y; val.z += f.z; val.w += f.w;
        }
    }
    val.x = fmaxf(val.x, 0.f); val.y = fmaxf(val.y, 0.f);
    val.z = fmaxf(val.z, 0.f); val.w = fmaxf(val.w, 0.f);
    *(float4*)(hout + (size_t)v * 128 + d) = val;
}

// ---------------- fused resnet layer: 4-way wave split per 16-row tile ------
// Block = 256 threads = 4 waves for ONE 16-row tile. wid&1 = K-half role
// (0: own rows K 0..127; 1: neighbor-agg K 128..255); wid>>1 = N-half
// (cols 0..63 / 64..127). Partials -> LDS psA/psB (132-stride, 2-way max
// bank aliasing = free), one barrier, then 256-thread coalesced float4
// epilogue: relu(psA+psB+bias)+h -> hnext.
struct LArgs {
    const float* h;                                   // [V][128] f32
    const unsigned short* Bp;                         // packed [64][2][512]
    const int* adj8;
    const float* bias;
    float* hnext;
    int V;
};

__global__ __launch_bounds__(256, 4) void lay_kernel(LArgs g) {
    __shared__ float psA[16][132];   // agg partial (role_k=1)
    __shared__ float psB[16][132];   // own partial (role_k=0)
    int tid = threadIdx.x;
    int wid = tid >> 6, l = tid & 63;
    int role_k = wid & 1, role_n = wid >> 1;
    int rowbase = xcd_swz(blockIdx.x, gridDim.x) * 16;
    int lrow = l & 15, lks = l >> 4;
    int grow = rowbase + lrow;
    bool act = grow < g.V;

    f32x4v acc[4];
#pragma unroll
    for (int nt = 0; nt < 4; ++nt) acc[nt] = (f32x4v){0.f, 0.f, 0.f, 0.f};

    if (role_k == 0) {
        // ---- own half: K 0..127, coalesced row stream ----
        const float* hp = g.h + (size_t)grow * 128;
#pragma unroll
        for (int ks = 0; ks < 4; ++ks) {
            int kb = ks * 32 + lks * 8;
            float a[8];
            if (act) {
                float4 f0 = *(const float4*)(hp + kb);
                float4 f1 = *(const float4*)(hp + kb + 4);
                a[0] = f0.x; a[1] = f0.y; a[2] = f0.z; a[3] = f0.w;
                a[4] = f1.x; a[5] = f1.y; a[6] = f1.z; a[7] = f1.w;
            } else {
#pragma unroll
                for (int i = 0; i < 8; ++i) a[i] = 0.f;
            }
            unsigned short hh[8], ll[8];
#pragma unroll
            for (int i = 0; i < 8; ++i) f2hl(a[i], hh[i], ll[i]);
            bf16x8v ah = *(const bf16x8v*)hh;
            bf16x8v al = *(const bf16x8v*)ll;
#pragma unroll
            for (int nt = 0; nt < 4; ++nt) {
                int ntg = role_n * 4 + nt;
                const unsigned short* p = g.Bp + (size_t)(ks * 8 + ntg) * 1024 + l * 8;
                bf16x8v bh = *(const bf16x8v*)p;
                bf16x8v bl = *(const bf16x8v*)(p + 512);
                acc[nt] = __builtin_amdgcn_mfma_f32_16x16x32_bf16(ah, bh, acc[nt], 0, 0, 0);
                acc[nt] = __builtin_amdgcn_mfma_f32_16x16x32_bf16(ah, bl, acc[nt], 0, 0, 0);
                acc[nt] = __builtin_amdgcn_mfma_f32_16x16x32_bf16(al, bh, acc[nt], 0, 0, 0);
            }
        }
    } else {
        // ---- agg half: K 128..255, 6 independent neighbor-row gathers ----
        int n[6];
        if (act) {
            const int* ap = g.adj8 + (size_t)grow * 8;
#pragma unroll
            for (int i = 0; i < 6; ++i) n[i] = ap[i];
        } else {
#pragma unroll
            for (int i = 0; i < 6; ++i) n[i] = -1;
        }
#pragma unroll
        for (int ks = 0; ks < 4; ++ks) {
            int ko = ks * 32 + lks * 8;
            float a[8];
#pragma unroll
            for (int i = 0; i < 8; ++i) a[i] = 0.f;
#pragma unroll
            for (int i = 0; i < 6; ++i) {
                if (n[i] >= 0) {
                    const float* hp = g.h + (size_t)n[i] * 128 + ko;
                    float4 f0 = *(const float4*)hp;
                    float4 f1 = *(const float4*)(hp + 4);
                    a[0] += f0.x; a[1] += f0.y; a[2] += f0.z; a[3] += f0.w;
                    a[4] += f1.x; a[5] += f1.y; a[6] += f1.z; a[7] += f1.w;
                }
            }
            unsigned short hh[8], ll[8];
#pragma unroll
            for (int i = 0; i < 8; ++i) f2hl(a[i], hh[i], ll[i]);
            bf16x8v ah = *(const bf16x8v*)hh;
            bf16x8v al = *(const bf16x8v*)ll;
#pragma unroll
            for (int nt = 0; nt < 4; ++nt) {
                int ntg = role_n * 4 + nt;
                const unsigned short* p = g.Bp + (size_t)((ks + 4) * 8 + ntg) * 1024 + l * 8;
                bf16x8v bh = *(const bf16x8v*)p;
                bf16x8v bl = *(const bf16x8v*)(p + 512);
                acc[nt] = __builtin_amdgcn_mfma_f32_16x16x32_bf16(ah, bh, acc[nt], 0, 0, 0);
                acc[nt] = __builtin_amdgcn_mfma_f32_16x16x32_bf16(ah, bl, acc[nt], 0, 0, 0);
                acc[nt] = __builtin_amdgcn_mfma_f32_16x16x32_bf16(al, bh, acc[nt], 0, 0, 0);
            }
        }
    }

    // ---- stash partials (disjoint col halves per role_n; 2-way bank max) ---
    {
        float(*ps)[132] = role_k ? psA : psB;
#pragma unroll
        for (int nt = 0; nt < 4; ++nt) {
            int col = role_n * 64 + nt * 16 + lrow;
#pragma unroll
            for (int r = 0; r < 4; ++r) ps[lks * 4 + r][col] = acc[nt][r];
        }
    }
    __syncthreads();

    // ---- cooperative coalesced epilogue: 256 threads, float4 ----
    int erow = tid >> 5;          // 0..7
    int ecol = (tid & 31) * 4;    // 0..124
    float4 b4 = *(const float4*)(g.bias + ecol);
#pragma unroll
    for (int rr = 0; rr < 2; ++rr) {
        int row = rr * 8 + erow;
        int rowg = rowbase + row;
        if (rowg < g.V) {
            float4 s;
            s.x = psA[row][ecol + 0] + psB[row][ecol + 0] + b4.x;
            s.y = psA[row][ecol + 1] + psB[row][ecol + 1] + b4.y;
            s.z = psA[row][ecol + 2] + psB[row][ecol + 2] + b4.z;
            s.w = psA[row][ecol + 3] + psB[row][ecol + 3] + b4.w;
            s.x = fmaxf(s.x, 0.f); s.y = fmaxf(s.y, 0.f);
            s.z = fmaxf(s.z, 0.f); s.w = fmaxf(s.w, 0.f);
            float4 hres = *(const float4*)(g.h + (size_t)rowg * 128 + ecol);
            s.x += hres.x; s.y += hres.y; s.z += hres.z; s.w += hres.w;
            *(float4*)(g.hnext + (size_t)rowg * 128 + ecol) = s;
        }
    }
}

// ---------------- coord head ------------------------------------------------
__global__ void coordgemm_kernel(const float* __restrict__ h,
                                 const float* __restrict__ Wc0, const float* __restrict__ Wc1,
                                 int V, float* __restrict__ Yc) {
    int idx = blockIdx.x * 256 + threadIdx.x;
    if (idx >= V * 6) return;
    int v = idx / 6, j = idx % 6;
    const float* W = (j < 3) ? Wc0 : Wc1;
    int jj = (j < 3) ? j : j - 3;
    const float* hp = h + (size_t)v * 128;
    float acc = 0.0f;
#pragma unroll
    for (int k = 0; k < 32; ++k) {
        float4 f = *(const float4*)(hp + k * 4);
        acc += f.x * W[(k * 4 + 0) * 3 + jj];
        acc += f.y * W[(k * 4 + 1) * 3 + jj];
        acc += f.z * W[(k * 4 + 2) * 3 + jj];
        acc += f.w * W[(k * 4 + 3) * 3 + jj];
    }
    Yc[idx] = acc;
}

__global__ void coordcombine_kernel(const float* __restrict__ Yc, const float* __restrict__ bc,
                                    const int* __restrict__ adj8,
                                    int V, float* __restrict__ out) {
    int idx = blockIdx.x * 256 + threadIdx.x;
    if (idx >= V * 3) return;
    int v = idx / 3, j = idx % 3;
    float val = Yc[(size_t)v * 6 + j] + bc[j];
    const int* ap = adj8 + (size_t)v * 8;
    int n[6];
#pragma unroll
    for (int i = 0; i < 6; ++i) n[i] = ap[i];
#pragma unroll
    for (int i = 0; i < 6; ++i)
        if (n[i] >= 0) val += Yc[(size_t)n[i] * 6 + 3 + j];
    out[(size_t)v * 3 + j] = val;
}

// ---------------- unpool: verts midpoints + featpack hi/lo ------------------
__global__ void unpool_kernel(float* __restrict__ verts, const float* __restrict__ h,
                              const int* __restrict__ mid, int V, int Nm,
                              unsigned short* __restrict__ fphi, unsigned short* __restrict__ fplo) {
    int r = blockIdx.x;
    int t = threadIdx.x;  // 128
    if (r < V) {
        float v = h[(size_t)r * 128 + t];
        unsigned short hi, lo;
        f2hl(v, hi, lo);
        fphi[(size_t)r * 128 + t] = hi;
        fplo[(size_t)r * 128 + t] = lo;
    } else {
        int i = r - V;
        int a = mid[2 * i], b = mid[2 * i + 1];
        float v = 0.5f * (h[(size_t)a * 128 + t] + h[(size_t)b * 128 + t]);
        unsigned short hi, lo;
        f2hl(v, hi, lo);
        fphi[(size_t)r * 128 + t] = hi;
        fplo[(size_t)r * 128 + t] = lo;
        if (t < 3)
            verts[(size_t)r * 3 + t] = 0.5f * (verts[(size_t)a * 3 + t] + verts[(size_t)b * 3 + t]);
    }
}

// ---------------------------------------------------------------------------
extern "C" void kernel_launch(void* const* d_in, const int* in_sizes, int n_in,
                              void* d_out, int out_size, void* d_ws, size_t ws_size,
                              hipStream_t stream) {
    const float* f3 = (const float*)d_in[0];
    const float* f4 = (const float*)d_in[1];
    const float* f5 = (const float*)d_in[2];
    const float* verts0 = (const float*)d_in[3];
    const float* cam_c = (const float*)d_in[4];
    const float* cam_f = (const float*)d_in[5];
    const int* imgsz = (const int*)d_in[38];

    int V0 = in_sizes[3] / 3;
    int E[3] = {in_sizes[33] / 2, in_sizes[34] / 2, in_sizes[35] / 2};
    int Nm0 = in_sizes[36] / 2, Nm1 = in_sizes[37] / 2;
    int V1 = V0 + Nm0, V2 = V1 + Nm1;
    int Vs[3] = {V0, V1, V2};
    const int NPIXT = 3136 + 784 + 196;  // 4116
    const int GS = NPIXT * 256;          // per-stage G stride (floats)

    // ---- workspace (byte allocator, 256B aligned) ----
    char* wsp = (char*)d_ws;
    auto alloc = [&](size_t bytes) -> void* {
        void* p = (void*)wsp;
        wsp += (bytes + 255) & ~(size_t)255;
        return p;
    };
    unsigned short* ft0h = (unsigned short*)alloc((size_t)3136 * 256 * 2);
    unsigned short* ft0l = (unsigned short*)alloc((size_t)3136 * 256 * 2);
    unsigned short* ft1h = (unsigned short*)alloc((size_t)784 * 512 * 2);
    unsigned short* ft1l = (unsigned short*)alloc((size_t)784 * 512 * 2);
    unsigned short* ft2h = (unsigned short*)alloc((size_t)196 * 512 * 2);
    unsigned short* ft2l = (unsigned short*)alloc((size_t)196 * 512 * 2);
    unsigned short* Bg0h = (unsigned short*)alloc((size_t)768 * 256 * 2);
    unsigned short* Bg0l = (unsigned short*)alloc((size_t)768 * 256 * 2);
    unsigned short* Bg1h = (unsigned short*)alloc((size_t)768 * 512 * 2);
    unsigned short* Bg1l = (unsigned short*)alloc((size_t)768 * 512 * 2);
    unsigned short* Bg2h = (unsigned short*)alloc((size_t)768 * 512 * 2);
    unsigned short* Bg2l = (unsigned short*)alloc((size_t)768 * 512 * 2);
    float* Gbuf = (float*)alloc((size_t)3 * GS * 4);
    unsigned short* BtLp[3];
    for (int s = 0; s < 3; ++s)
        BtLp[s] = (unsigned short*)alloc((size_t)12 * 65536 * 2);  // fragment-packed hi+lo
    unsigned short* BtShi[2];
    unsigned short* BtSlo[2];
    for (int s = 0; s < 2; ++s) {
        BtShi[s] = (unsigned short*)alloc((size_t)256 * 128 * 2);
        BtSlo[s] = (unsigned short*)alloc((size_t)256 * 128 * 2);
    }
    float* Ybuf = (float*)alloc((size_t)V2 * 256 * 4);
    float* hA = (float*)alloc((size_t)V2 * 128 * 4);
    float* hB = (float*)alloc((size_t)V2 * 128 * 4);
    unsigned short* FPhi = (unsigned short*)alloc((size_t)V2 * 128 * 2);
    unsigned short* FPlo = (unsigned short*)alloc((size_t)V2 * 128 * 2);
    float* vertsbuf = (float*)alloc((size_t)V2 * 3 * 4);
    float* Yc = (float*)alloc((size_t)V2 * 6 * 4);
    int* sampi = (int*)alloc((size_t)V2 * 12 * 4);
    float* sampw = (float*)alloc((size_t)V2 * 12 * 4);
    int* adj8 = (int*)alloc((size_t)V2 * 8 * 4);

    // ---- feature map transpose + hi/lo split ----
    transpose_hl<<<DIV_UP(256 * 56 * 56, 256), 256, 0, stream>>>(f3, ft0h, ft0l, 256, 56 * 56);
    transpose_hl<<<DIV_UP(512 * 28 * 28, 256), 256, 0, stream>>>(f4, ft1h, ft1l, 512, 28 * 28);
    transpose_hl<<<DIV_UP(512 * 14 * 14, 256), 256, 0, stream>>>(f5, ft2h, ft2l, 512, 14 * 14);

    // ---- single fused weight pack ----
    {
        PackArgs p;
        for (int s = 0; s < 3; ++s) {
            p.Win0[s] = (const float*)d_in[6 + s * 9 + 0];
            p.Win1[s] = (const float*)d_in[6 + s * 9 + 1];
            p.W0L[s] = (const float*)d_in[6 + s * 9 + 3];
            p.W1L[s] = (const float*)d_in[6 + s * 9 + 4];
            p.BtLp[s] = BtLp[s];
        }
        p.BtShi[0] = BtShi[0]; p.BtSlo[0] = BtSlo[0];
        p.BtShi[1] = BtShi[1]; p.BtSlo[1] = BtSlo[1];
        p.Bgh[0] = Bg0h; p.Bgl[0] = Bg0l;
        p.Bgh[1] = Bg1h; p.Bgl[1] = Bg1l;
        p.Bgh[2] = Bg2h; p.Bgl[2] = Bg2l;
        int total = 3 * 12 * 32768 + 2 * 256 * 128 + 768 * 256 + 2 * 768 * 512;
        pack_all<<<DIV_UP(total, 256), 256, 0, stream>>>(p);
    }

    // ---- G precompute (MFMA): G[s][pix][256] = ft_m @ W-slice ----
    {
        MArgs m = {};
        m.sstr = GS;
        m.Ahi = ft0h; m.Alo = ft0l; m.lda = 256;
        m.Bhi = Bg0h; m.Blo = Bg0l; m.K = 256;
        m.Y = Gbuf; m.V = 3136;
        dim3 g0(6, DIV_UP(3136, 64));
        mgemm<2><<<g0, 256, 0, stream>>>(m);
        m.Ahi = ft1h; m.Alo = ft1l; m.lda = 512;
        m.Bhi = Bg1h; m.Blo = Bg1l; m.K = 512;
        m.Y = Gbuf + (size_t)3136 * 256; m.V = 784;
        dim3 g1(6, DIV_UP(784, 64));
        mgemm<2><<<g1, 256, 0, stream>>>(m);
        m.Ahi = ft2h; m.Alo = ft2l; m.lda = 512;
        m.Bhi = Bg2h; m.Blo = Bg2l; m.K = 512;
        m.Y = Gbuf + (size_t)3920 * 256; m.V = 196;
        dim3 g2(6, DIV_UP(196, 64));
        mgemm<2><<<g2, 256, 0, stream>>>(m);
    }

    for (int si = 0; si < 3; ++si) {
        const float* Win0 = (const float*)d_in[6 + si * 9 + 0];
        const float* Win1 = (const float*)d_in[6 + si * 9 + 1];
        const float* bin = (const float*)d_in[6 + si * 9 + 2];
        const float* bs = (const float*)d_in[6 + si * 9 + 5];
        const float* Wc0 = (const float*)d_in[6 + si * 9 + 6];
        const float* Wc1 = (const float*)d_in[6 + si * 9 + 7];
        const float* bc = (const float*)d_in[6 + si * 9 + 8];
        const int* edges = (const int*)d_in[33 + si];
        int Ecur = E[si];
        const int* esrc = edges;
        const int* edst = edges + Ecur;
        int V = Vs[si];
        const float* vertsin = (si == 0) ? verts0 : vertsbuf;

        desc_adj_kernel<<<DIV_UP(V, 256), 256, 0, stream>>>(vertsin, cam_c, cam_f, imgsz, V,
                                                            esrc, edst, Ecur, sampi, sampw, adj8);
        // shape GEMM first (pure store), then gather adds perceptual part
        if (si > 0) {
            MArgs m = {};
            m.Ahi = FPhi; m.Alo = FPlo; m.lda = 128;
            m.Bhi = BtShi[si - 1]; m.Blo = BtSlo[si - 1]; m.K = 128;
            m.Y = Ybuf; m.V = V;
            dim3 grid(2, DIV_UP(V, 64));
            mgemm<3><<<grid, 256, 0, stream>>>(m);
        }
        gather_kernel<<<DIV_UP(V, 4), 256, 0, stream>>>(Gbuf, GS, sampi, sampw, Ybuf, V, si,
                                                        Win0, Win1, (si == 0) ? verts0 : nullptr);
        combine_in<<<DIV_UP(V, 8), 256, 0, stream>>>(Ybuf, bin, adj8, hA, V);

        float* hcur = hA;
        float* hnext = hB;
        for (int ll = 0; ll < 12; ++ll) {
            LArgs a = {};
            a.h = hcur;
            a.Bp = BtLp[si] + (size_t)ll * 65536;
            a.adj8 = adj8;
            a.bias = bs + (size_t)ll * 128;
            a.hnext = hnext;
            a.V = V;
            lay_kernel<<<DIV_UP(V, 16), 256, 0, stream>>>(a);
            float* t = hcur; hcur = hnext; hnext = t;
        }

        coordgemm_kernel<<<DIV_UP(V * 6, 256), 256, 0, stream>>>(hcur, Wc0, Wc1, V, Yc);
        float* ctarget = (si == 2) ? (float*)d_out : vertsbuf;
        coordcombine_kernel<<<DIV_UP(V * 3, 256), 256, 0, stream>>>(Yc, bc, adj8, V, ctarget);
        if (si < 2) {
            const int* mid = (const int*)d_in[36 + si];
            int Nm = (si == 0) ? Nm0 : Nm1;
            unpool_kernel<<<V + Nm, 128, 0, stream>>>(vertsbuf, hcur, mid, V, Nm, FPhi, FPlo);
        }
    }
}

// Round 10
// 1328.276 us; speedup vs baseline: 1.6043x; 1.0425x over previous
//
#include <hip/hip_runtime.h>
#include <hip/hip_bf16.h>
#include <cstddef>
#include <cstdint>

#define DIV_UP(a, b) (((a) + (b) - 1) / (b))

typedef __attribute__((ext_vector_type(8))) short bf16x8v;
typedef __attribute__((ext_vector_type(4))) float f32x4v;

__device__ __forceinline__ unsigned short bf16_rn(float v) {
    unsigned int u = __float_as_uint(v);
    unsigned int r = (u + 0x7FFFu + ((u >> 16) & 1u)) >> 16;
    return (unsigned short)r;
}
__device__ __forceinline__ float bf16_f(unsigned short h) {
    return __uint_as_float(((unsigned int)h) << 16);
}
__device__ __forceinline__ void f2hl(float v, unsigned short& hi, unsigned short& lo) {
    hi = bf16_rn(v);
    float r = v - bf16_f(hi);
    lo = bf16_rn(r);
}
__device__ __forceinline__ int xcd_swz(int orig, int nwg) {
    int q = nwg >> 3, r = nwg & 7;
    int xcd = orig & 7, idx = orig >> 3;
    return (xcd < r ? xcd * (q + 1) : r * (q + 1) + (xcd - r) * q) + idx;
}

// ---------------- transpose (C,H,W) f32 -> (H*W, C) bf16 hi/lo --------------
__global__ void transpose_hl(const float* __restrict__ in, unsigned short* __restrict__ ohi,
                             unsigned short* __restrict__ olo, int C, int HW) {
    int idx = blockIdx.x * 256 + threadIdx.x;
    if (idx >= C * HW) return;
    int c = idx % C;
    int p = idx / C;
    float v = in[(size_t)c * HW + p];
    unsigned short hi, lo;
    f2hl(v, hi, lo);
    ohi[(size_t)p * C + c] = hi;
    olo[(size_t)p * C + c] = lo;
}

// ---------------- single fused weight-pack kernel ---------------------------
// Layer weights packed in MFMA-fragment order:
//   BtLp[st][layer][ks(8)][nt(8)][hl(2)][lane(64)][i(8)]
struct PackArgs {
    const float* Win0[3]; const float* Win1[3];   // [1408|1283][128]
    const float* W0L[3];  const float* W1L[3];    // [12][128][128]
    unsigned short* BtLp[3];                      // [12][64][2][512]
    unsigned short *BtShi[2], *BtSlo[2];          // stages 1,2: [256][128]
    unsigned short *Bgh[3], *Bgl[3];              // [768][C] C=256,512,512
};

__global__ void pack_all(PackArgs p) {
    const int LAY1 = 12 * 32768;               // 393216 per stage
    const int LAYT = 3 * LAY1;                 // 1179648
    const int SH1 = 256 * 128;                 // 32768 per stage
    const int SHT = 2 * SH1;
    const int GB0 = 768 * 256, GB1 = 768 * 512;
    int idx = blockIdx.x * 256 + threadIdx.x;
    if (idx < LAYT) {
        int st = idx / LAY1, r = idx % LAY1;
        int layer = r >> 15, q = r & 32767;
        int ks = q >> 12, nt = (q >> 9) & 7, lane = (q >> 3) & 63, i = q & 7;
        int n = nt * 16 + (lane & 15);
        int k = ks * 32 + ((lane >> 4) << 3) + i;
        float v = (k < 128) ? p.W0L[st][(size_t)layer * 16384 + k * 128 + n]
                            : p.W1L[st][(size_t)layer * 16384 + (k - 128) * 128 + n];
        unsigned short hi, lo;
        f2hl(v, hi, lo);
        size_t base = ((size_t)layer * 64 + ks * 8 + nt) * 1024 + lane * 8 + i;
        p.BtLp[st][base] = hi;
        p.BtLp[st][base + 512] = lo;
        return;
    }
    float v;
    unsigned short* dh;
    unsigned short* dl;
    size_t o;
    if (idx < LAYT + SHT) {
        int q = idx - LAYT;
        int st = q / SH1, rr = q % SH1;
        int n = rr >> 7, k = rr & 127;
        const float* w0 = p.Win0[st + 1];
        const float* w1 = p.Win1[st + 1];
        v = (n < 128) ? w0[(size_t)(1280 + k) * 128 + n]
                      : w1[(size_t)(1280 + k) * 128 + (n - 128)];
        dh = p.BtShi[st]; dl = p.BtSlo[st]; o = rr;
    } else {
        int q = idx - LAYT - SHT;
        int m, C, base;
        if (q < GB0) { m = 0; C = 256; base = 0; }
        else if (q < GB0 + GB1) { m = 1; C = 512; base = 256; q -= GB0; }
        else if (q < GB0 + 2 * GB1) { m = 2; C = 512; base = 768; q -= GB0 + GB1; }
        else return;
        int n = q / C, k = q % C;
        int s = n >> 8, j = n & 255;
        v = (j < 128) ? p.Win0[s][(size_t)(base + k) * 128 + j]
                      : p.Win1[s][(size_t)(base + k) * 128 + (j - 128)];
        dh = p.Bgh[m]; dl = p.Bgl[m]; o = q;
    }
    unsigned short hi, lo;
    f2hl(v, hi, lo);
    dh[o] = hi;
    dl[o] = lo;
}

// -------- per-vertex projection/bilerp descriptors + fixed-degree adj -------
__global__ void desc_adj_kernel(const float* __restrict__ verts,
                                const float* __restrict__ cam_c, const float* __restrict__ cam_f,
                                const int* __restrict__ imgsz, int V,
                                const int* __restrict__ src, const int* __restrict__ dst, int E,
                                int* __restrict__ sampi, float* __restrict__ sampw,
                                int* __restrict__ adj8) {
    int v = blockIdx.x * 256 + threadIdx.x;
    if (v >= V) return;
    float X = verts[3 * v + 0], Yy = verts[3 * v + 1], Z = verts[3 * v + 2];
    float cx = cam_c[0], cy = cam_c[1], fx = cam_f[0], fy = cam_f[1];
    const float tz = 0.8f;
    float pz = Z + tz;
    float px = (fx * X + cx * Z + tz * cx) / pz;
    float py = (fy * Yy + cy * Z + tz * cy) / pz;
    float is = (float)imgsz[0];
    const int Ss[3] = {56, 28, 14};
#pragma unroll
    for (int m = 0; m < 3; ++m) {
        int S = Ss[m];
        float dim = (float)S;
        float x = px * dim / is;
        float y = py * dim / is;
        float x1 = floorf(x), y1 = floorf(y);
        float x2 = x1 + 1.0f, y2 = y1 + 1.0f;
        float smax = (float)(S - 1);
        int xi1 = (int)fminf(fmaxf(x1, 0.0f), smax);
        int xi2 = (int)fminf(fmaxf(x2, 0.0f), smax);
        int yi1 = (int)fminf(fmaxf(y1, 0.0f), smax);
        int yi2 = (int)fminf(fmaxf(y2, 0.0f), smax);
        int b = v * 12 + m * 4;
        sampi[b + 0] = xi1 * S + yi1;
        sampi[b + 1] = xi1 * S + yi2;
        sampi[b + 2] = xi2 * S + yi1;
        sampi[b + 3] = xi2 * S + yi2;
        sampw[b + 0] = (x2 - x) * (y2 - y);
        sampw[b + 1] = (x2 - x) * (y - y1);
        sampw[b + 2] = (x - x1) * (y2 - y);
        sampw[b + 3] = (x - x1) * (y - y1);
    }
    // fixed-degree adjacency via two binary searches on sorted src
    int lo = 0, hi = E;
    while (lo < hi) { int m = (lo + hi) >> 1; if (src[m] < v) lo = m + 1; else hi = m; }
    int e0 = lo;
    hi = E;
    while (lo < hi) { int m = (lo + hi) >> 1; if (src[m] < v + 1) lo = m + 1; else hi = m; }
    int e1 = lo;
    int* ap = adj8 + (size_t)v * 8;
#pragma unroll
    for (int i = 0; i < 8; ++i) {
        int e = e0 + i;
        ap[i] = (e < e1) ? dst[e] : -1;
    }
}

// ---------------- zero the pad row (index V) of both h buffers --------------
__global__ void zero_pad(float* __restrict__ a, float* __restrict__ b) {
    int t = threadIdx.x;  // 128
    a[t] = 0.0f;
    b[t] = 0.0f;
}

// ---------------- MFMA bf16x3 GEMM (G precompute + shape GEMM) --------------
struct MArgs {
    const unsigned short *Ahi, *Alo; int lda;
    const unsigned short *Bhi, *Blo; int K;  // Bt row-major [N][K]
    float* Y;
    int sstr;
    int V;
};

template <int EPI>
__global__ __launch_bounds__(256) void mgemm(MArgs g) {
    __shared__ unsigned short As_hi[64][40], As_lo[64][40];
    __shared__ unsigned short Bs_hi[128][40], Bs_lo[128][40];
    int tid = threadIdx.x;
    int row0 = blockIdx.y * 64;
    int col0 = blockIdx.x * 128;
    int l = tid & 63, wid = tid >> 6;
    int wr = wid & 1, wc = wid >> 1;
    int lw = l & 15, gg = l >> 4;
    f32x4v acc[2][4];
#pragma unroll
    for (int i = 0; i < 2; ++i)
#pragma unroll
        for (int j = 0; j < 4; ++j) acc[i][j] = (f32x4v){0.f, 0.f, 0.f, 0.f};

    int arow = tid >> 2, akoff = (tid & 3) * 8;
    for (int k0 = 0; k0 < g.K; k0 += 32) {
        __syncthreads();
        {
            int grow = row0 + arow;
            uint4 zh = make_uint4(0, 0, 0, 0), zl = make_uint4(0, 0, 0, 0);
            if (grow < g.V) {
                zh = *(const uint4*)(g.Ahi + (size_t)grow * g.lda + k0 + akoff);
                zl = *(const uint4*)(g.Alo + (size_t)grow * g.lda + k0 + akoff);
            }
            *(uint4*)&As_hi[arow][akoff] = zh;
            *(uint4*)&As_lo[arow][akoff] = zl;
        }
#pragma unroll
        for (int it = 0; it < 2; ++it) {
            int q = tid + it * 256;
            int n = q >> 2, koff = (q & 3) * 8;
            *(uint4*)&Bs_hi[n][koff] = *(const uint4*)(g.Bhi + (size_t)(col0 + n) * g.K + k0 + koff);
            *(uint4*)&Bs_lo[n][koff] = *(const uint4*)(g.Blo + (size_t)(col0 + n) * g.K + k0 + koff);
        }
        __syncthreads();
        bf16x8v ah[2], al[2], bh[4], bl[4];
#pragma unroll
        for (int mt = 0; mt < 2; ++mt) {
            int r = wr * 32 + mt * 16 + lw;
            ah[mt] = *(const bf16x8v*)&As_hi[r][gg * 8];
            al[mt] = *(const bf16x8v*)&As_lo[r][gg * 8];
        }
#pragma unroll
        for (int nt = 0; nt < 4; ++nt) {
            int c = wc * 64 + nt * 16 + lw;
            bh[nt] = *(const bf16x8v*)&Bs_hi[c][gg * 8];
            bl[nt] = *(const bf16x8v*)&Bs_lo[c][gg * 8];
        }
#pragma unroll
        for (int mt = 0; mt < 2; ++mt)
#pragma unroll
            for (int nt = 0; nt < 4; ++nt) {
                acc[mt][nt] = __builtin_amdgcn_mfma_f32_16x16x32_bf16(ah[mt], bh[nt], acc[mt][nt], 0, 0, 0);
                acc[mt][nt] = __builtin_amdgcn_mfma_f32_16x16x32_bf16(ah[mt], bl[nt], acc[mt][nt], 0, 0, 0);
                acc[mt][nt] = __builtin_amdgcn_mfma_f32_16x16x32_bf16(al[mt], bh[nt], acc[mt][nt], 0, 0, 0);
            }
    }
#pragma unroll
    for (int mt = 0; mt < 2; ++mt)
#pragma unroll
        for (int nt = 0; nt < 4; ++nt) {
            int colg = wc * 64 + nt * 16 + lw;
#pragma unroll
            for (int r = 0; r < 4; ++r) {
                int rowg = row0 + wr * 32 + mt * 16 + gg * 4 + r;
                if (rowg >= g.V) continue;
                float v = acc[mt][nt][r];
                if (EPI == 3) {
                    g.Y[(size_t)rowg * 256 + col0 + colg] = v;
                } else {
                    int cg = col0 + colg;
                    g.Y[(size_t)(cg >> 8) * g.sstr + (size_t)rowg * 256 + (cg & 255)] = v;
                }
            }
        }
}

// ---------------- input perceptual gather (float4, 64 thr/vertex) -----------
__global__ void gather_kernel(const float* __restrict__ G, int sstr,
                              const int* __restrict__ sampi, const float* __restrict__ sampw,
                              float* __restrict__ Yb, int V, int stage,
                              const float* __restrict__ Win0, const float* __restrict__ Win1,
                              const float* __restrict__ shape) {
    int v = xcd_swz(blockIdx.x, gridDim.x) * 4 + (threadIdx.x >> 6);
    if (v >= V) return;
    int j = (threadIdx.x & 63) * 4;
    const float* Gs = G + (size_t)stage * sstr;
    int b = v * 12;
    float4 acc;
    if (stage == 0) acc = make_float4(0.f, 0.f, 0.f, 0.f);
    else acc = *(const float4*)(Yb + (size_t)v * 256 + j);
#pragma unroll
    for (int s = 0; s < 4; ++s) {
        float w = sampw[b + s];
        float4 f = *(const float4*)(Gs + (size_t)sampi[b + s] * 256 + j);
        acc.x += w * f.x; acc.y += w * f.y; acc.z += w * f.z; acc.w += w * f.w;
    }
#pragma unroll
    for (int s = 0; s < 4; ++s) {
        float w = sampw[b + 4 + s];
        float4 f = *(const float4*)(Gs + (size_t)(3136 + sampi[b + 4 + s]) * 256 + j);
        acc.x += w * f.x; acc.y += w * f.y; acc.z += w * f.z; acc.w += w * f.w;
    }
#pragma unroll
    for (int s = 0; s < 4; ++s) {
        float w = sampw[b + 8 + s];
        float4 f = *(const float4*)(Gs + (size_t)(3920 + sampi[b + 8 + s]) * 256 + j);
        acc.x += w * f.x; acc.y += w * f.y; acc.z += w * f.z; acc.w += w * f.w;
    }
    if (stage == 0) {
#pragma unroll
        for (int k = 0; k < 3; ++k) {
            float w = shape[v * 3 + k];
            const float* wr = (j < 128) ? Win0 + (size_t)(1280 + k) * 128 + j
                                        : Win1 + (size_t)(1280 + k) * 128 + (j - 128);
            float4 wv = *(const float4*)wr;
            acc.x += w * wv.x; acc.y += w * wv.y; acc.z += w * wv.z; acc.w += w * wv.w;
        }
    }
    *(float4*)(Yb + (size_t)v * 256 + j) = acc;
}

// ---------------- input-layer combine (float4, 32 thr/vertex) ---------------
__global__ __launch_bounds__(256) void combine_in(
    const float* __restrict__ Y, const float* __restrict__ bias,
    const int* __restrict__ adj8,
    float* __restrict__ hout, int V) {
    int v = xcd_swz(blockIdx.x, gridDim.x) * 8 + (threadIdx.x >> 5);
    if (v >= V) return;
    int d = (threadIdx.x & 31) * 4;
    float4 val = *(const float4*)(Y + (size_t)v * 256 + d);
    float4 b4 = *(const float4*)(bias + d);
    val.x += b4.x; val.y += b4.y; val.z += b4.z; val.w += b4.w;
    const int* ap = adj8 + (size_t)v * 8;
    int n[6];
#pragma unroll
    for (int i = 0; i < 6; ++i) n[i] = ap[i];
#pragma unroll
    for (int i = 0; i < 6; ++i) {
        if (n[i] >= 0) {
            float4 f = *(const float4*)(Y + (size_t)n[i] * 256 + 128 + d);
            val.x += f.x; val.y += f.y; val.z += f.z; val.w += f.w;
        }
    }
    val.x = fmaxf(val.x, 0.f); val.y = fmaxf(val.y, 0.f);
    val.z = fmaxf(val.z, 0.f); val.w = fmaxf(val.w, 0.f);
    *(float4*)(hout + (size_t)v * 128 + d) = val;
}

// ---------------- fused resnet layer: 4-way wave split, pipelined gather ----
// Block = 256 threads = 4 waves for ONE 16-row tile. wid&1 = K-half role
// (0: own rows K 0..127; 1: neighbor-agg K 128..255); wid>>1 = N-half.
// Agg gather: invalid neighbors padded to zero-row index V (row V of h is
// kept zero), all 6 loads unconditional, double-buffered across k-steps with
// statically-indexed bufA/bufB (24 float4 in flight before first wait).
struct LArgs {
    const float* h;                                   // [V+1][128] f32 (row V = 0)
    const unsigned short* Bp;                         // packed [64][2][512]
    const int* adj8;
    const float* bias;
    float* hnext;
    int V;
};

__global__ __launch_bounds__(256, 2) void lay_kernel(LArgs g) {
    __shared__ float psA[16][132];   // agg partial (role_k=1)
    __shared__ float psB[16][132];   // own partial (role_k=0)
    int tid = threadIdx.x;
    int wid = tid >> 6, l = tid & 63;
    int role_k = wid & 1, role_n = wid >> 1;
    int rowbase = xcd_swz(blockIdx.x, gridDim.x) * 16;
    int lrow = l & 15, lks = l >> 4;
    int grow = rowbase + lrow;
    bool act = grow < g.V;

    f32x4v acc[4];
#pragma unroll
    for (int nt = 0; nt < 4; ++nt) acc[nt] = (f32x4v){0.f, 0.f, 0.f, 0.f};

    auto domfma = [&](const float* a, int ksg) {
        unsigned short hh[8], ll[8];
#pragma unroll
        for (int i = 0; i < 8; ++i) f2hl(a[i], hh[i], ll[i]);
        bf16x8v ah = *(const bf16x8v*)hh;
        bf16x8v al = *(const bf16x8v*)ll;
#pragma unroll
        for (int nt = 0; nt < 4; ++nt) {
            int ntg = role_n * 4 + nt;
            const unsigned short* p = g.Bp + (size_t)(ksg * 8 + ntg) * 1024 + l * 8;
            bf16x8v bh = *(const bf16x8v*)p;
            bf16x8v bl = *(const bf16x8v*)(p + 512);
            acc[nt] = __builtin_amdgcn_mfma_f32_16x16x32_bf16(ah, bh, acc[nt], 0, 0, 0);
            acc[nt] = __builtin_amdgcn_mfma_f32_16x16x32_bf16(ah, bl, acc[nt], 0, 0, 0);
            acc[nt] = __builtin_amdgcn_mfma_f32_16x16x32_bf16(al, bh, acc[nt], 0, 0, 0);
        }
    };

    if (role_k == 0) {
        // ---- own half: K 0..127, all 8 loads issued upfront ----
        const float* hp = g.h + (size_t)(act ? grow : g.V) * 128 + lks * 8;
        float4 own[8];
#pragma unroll
        for (int ks = 0; ks < 4; ++ks) {
            own[ks * 2] = *(const float4*)(hp + ks * 32);
            own[ks * 2 + 1] = *(const float4*)(hp + ks * 32 + 4);
        }
#pragma unroll
        for (int ks = 0; ks < 4; ++ks) {
            float a[8];
            *(float4*)&a[0] = own[ks * 2];
            *(float4*)&a[4] = own[ks * 2 + 1];
            domfma(a, ks);
        }
    } else {
        // ---- agg half: K 128..255, 6 unconditional gathers, 2-deep pipeline -
        const float* hp[6];
        {
            const int* ap = g.adj8 + (size_t)grow * 8;
#pragma unroll
            for (int i = 0; i < 6; ++i) {
                int t = act ? ap[i] : -1;
                int nb = (t >= 0) ? t : g.V;   // pad -> zero row
                hp[i] = g.h + (size_t)nb * 128 + lks * 8;
            }
        }
        float4 bufA[12], bufB[12];
        auto issue = [&](float4* buf, int ks) {
#pragma unroll
            for (int i = 0; i < 6; ++i) {
                buf[i * 2] = *(const float4*)(hp[i] + ks * 32);
                buf[i * 2 + 1] = *(const float4*)(hp[i] + ks * 32 + 4);
            }
        };
        auto consume = [&](const float4* buf, int ks) {
            float a[8];
#pragma unroll
            for (int i = 0; i < 8; ++i) a[i] = 0.f;
#pragma unroll
            for (int i = 0; i < 6; ++i) {
                a[0] += buf[i * 2].x; a[1] += buf[i * 2].y;
                a[2] += buf[i * 2].z; a[3] += buf[i * 2].w;
                a[4] += buf[i * 2 + 1].x; a[5] += buf[i * 2 + 1].y;
                a[6] += buf[i * 2 + 1].z; a[7] += buf[i * 2 + 1].w;
            }
            domfma(a, 4 + ks);
        };
        issue(bufA, 0);
        issue(bufB, 1);
        consume(bufA, 0);
        issue(bufA, 2);
        consume(bufB, 1);
        issue(bufB, 3);
        consume(bufA, 2);
        consume(bufB, 3);
    }

    // ---- stash partials (disjoint col halves per role_n; 2-way bank max) ---
    {
        float(*ps)[132] = role_k ? psA : psB;
#pragma unroll
        for (int nt = 0; nt < 4; ++nt) {
            int col = role_n * 64 + nt * 16 + lrow;
#pragma unroll
            for (int r = 0; r < 4; ++r) ps[lks * 4 + r][col] = acc[nt][r];
        }
    }
    __syncthreads();

    // ---- cooperative coalesced epilogue: 256 threads, float4 ----
    int erow = tid >> 5;          // 0..7
    int ecol = (tid & 31) * 4;    // 0..124
    float4 b4 = *(const float4*)(g.bias + ecol);
#pragma unroll
    for (int rr = 0; rr < 2; ++rr) {
        int row = rr * 8 + erow;
        int rowg = rowbase + row;
        if (rowg < g.V) {
            float4 s;
            s.x = psA[row][ecol + 0] + psB[row][ecol + 0] + b4.x;
            s.y = psA[row][ecol + 1] + psB[row][ecol + 1] + b4.y;
            s.z = psA[row][ecol + 2] + psB[row][ecol + 2] + b4.z;
            s.w = psA[row][ecol + 3] + psB[row][ecol + 3] + b4.w;
            s.x = fmaxf(s.x, 0.f); s.y = fmaxf(s.y, 0.f);
            s.z = fmaxf(s.z, 0.f); s.w = fmaxf(s.w, 0.f);
            float4 hres = *(const float4*)(g.h + (size_t)rowg * 128 + ecol);
            s.x += hres.x; s.y += hres.y; s.z += hres.z; s.w += hres.w;
            *(float4*)(g.hnext + (size_t)rowg * 128 + ecol) = s;
        }
    }
}

// ---------------- coord head ------------------------------------------------
__global__ void coordgemm_kernel(const float* __restrict__ h,
                                 const float* __restrict__ Wc0, const float* __restrict__ Wc1,
                                 int V, float* __restrict__ Yc) {
    int idx = blockIdx.x * 256 + threadIdx.x;
    if (idx >= V * 6) return;
    int v = idx / 6, j = idx % 6;
    const float* W = (j < 3) ? Wc0 : Wc1;
    int jj = (j < 3) ? j : j - 3;
    const float* hp = h + (size_t)v * 128;
    float acc = 0.0f;
#pragma unroll
    for (int k = 0; k < 32; ++k) {
        float4 f = *(const float4*)(hp + k * 4);
        acc += f.x * W[(k * 4 + 0) * 3 + jj];
        acc += f.y * W[(k * 4 + 1) * 3 + jj];
        acc += f.z * W[(k * 4 + 2) * 3 + jj];
        acc += f.w * W[(k * 4 + 3) * 3 + jj];
    }
    Yc[idx] = acc;
}

__global__ void coordcombine_kernel(const float* __restrict__ Yc, const float* __restrict__ bc,
                                    const int* __restrict__ adj8,
                                    int V, float* __restrict__ out) {
    int idx = blockIdx.x * 256 + threadIdx.x;
    if (idx >= V * 3) return;
    int v = idx / 3, j = idx % 3;
    float val = Yc[(size_t)v * 6 + j] + bc[j];
    const int* ap = adj8 + (size_t)v * 8;
    int n[6];
#pragma unroll
    for (int i = 0; i < 6; ++i) n[i] = ap[i];
#pragma unroll
    for (int i = 0; i < 6; ++i)
        if (n[i] >= 0) val += Yc[(size_t)n[i] * 6 + 3 + j];
    out[(size_t)v * 3 + j] = val;
}

// ---------------- unpool: verts midpoints + featpack hi/lo ------------------
__global__ void unpool_kernel(float* __restrict__ verts, const float* __restrict__ h,
                              const int* __restrict__ mid, int V, int Nm,
                              unsigned short* __restrict__ fphi, unsigned short* __restrict__ fplo) {
    int r = blockIdx.x;
    int t = threadIdx.x;  // 128
    if (r < V) {
        float v = h[(size_t)r * 128 + t];
        unsigned short hi, lo;
        f2hl(v, hi, lo);
        fphi[(size_t)r * 128 + t] = hi;
        fplo[(size_t)r * 128 + t] = lo;
    } else {
        int i = r - V;
        int a = mid[2 * i], b = mid[2 * i + 1];
        float v = 0.5f * (h[(size_t)a * 128 + t] + h[(size_t)b * 128 + t]);
        unsigned short hi, lo;
        f2hl(v, hi, lo);
        fphi[(size_t)r * 128 + t] = hi;
        fplo[(size_t)r * 128 + t] = lo;
        if (t < 3)
            verts[(size_t)r * 3 + t] = 0.5f * (verts[(size_t)a * 3 + t] + verts[(size_t)b * 3 + t]);
    }
}

// ---------------------------------------------------------------------------
extern "C" void kernel_launch(void* const* d_in, const int* in_sizes, int n_in,
                              void* d_out, int out_size, void* d_ws, size_t ws_size,
                              hipStream_t stream) {
    const float* f3 = (const float*)d_in[0];
    const float* f4 = (const float*)d_in[1];
    const float* f5 = (const float*)d_in[2];
    const float* verts0 = (const float*)d_in[3];
    const float* cam_c = (const float*)d_in[4];
    const float* cam_f = (const float*)d_in[5];
    const int* imgsz = (const int*)d_in[38];

    int V0 = in_sizes[3] / 3;
    int E[3] = {in_sizes[33] / 2, in_sizes[34] / 2, in_sizes[35] / 2};
    int Nm0 = in_sizes[36] / 2, Nm1 = in_sizes[37] / 2;
    int V1 = V0 + Nm0, V2 = V1 + Nm1;
    int Vs[3] = {V0, V1, V2};
    const int NPIXT = 3136 + 784 + 196;  // 4116
    const int GS = NPIXT * 256;          // per-stage G stride (floats)

    // ---- workspace (byte allocator, 256B aligned) ----
    char* wsp = (char*)d_ws;
    auto alloc = [&](size_t bytes) -> void* {
        void* p = (void*)wsp;
        wsp += (bytes + 255) & ~(size_t)255;
        return p;
    };
    unsigned short* ft0h = (unsigned short*)alloc((size_t)3136 * 256 * 2);
    unsigned short* ft0l = (unsigned short*)alloc((size_t)3136 * 256 * 2);
    unsigned short* ft1h = (unsigned short*)alloc((size_t)784 * 512 * 2);
    unsigned short* ft1l = (unsigned short*)alloc((size_t)784 * 512 * 2);
    unsigned short* ft2h = (unsigned short*)alloc((size_t)196 * 512 * 2);
    unsigned short* ft2l = (unsigned short*)alloc((size_t)196 * 512 * 2);
    unsigned short* Bg0h = (unsigned short*)alloc((size_t)768 * 256 * 2);
    unsigned short* Bg0l = (unsigned short*)alloc((size_t)768 * 256 * 2);
    unsigned short* Bg1h = (unsigned short*)alloc((size_t)768 * 512 * 2);
    unsigned short* Bg1l = (unsigned short*)alloc((size_t)768 * 512 * 2);
    unsigned short* Bg2h = (unsigned short*)alloc((size_t)768 * 512 * 2);
    unsigned short* Bg2l = (unsigned short*)alloc((size_t)768 * 512 * 2);
    float* Gbuf = (float*)alloc((size_t)3 * GS * 4);
    unsigned short* BtLp[3];
    for (int s = 0; s < 3; ++s)
        BtLp[s] = (unsigned short*)alloc((size_t)12 * 65536 * 2);  // fragment-packed hi+lo
    unsigned short* BtShi[2];
    unsigned short* BtSlo[2];
    for (int s = 0; s < 2; ++s) {
        BtShi[s] = (unsigned short*)alloc((size_t)256 * 128 * 2);
        BtSlo[s] = (unsigned short*)alloc((size_t)256 * 128 * 2);
    }
    float* Ybuf = (float*)alloc((size_t)V2 * 256 * 4);
    float* hA = (float*)alloc(((size_t)V2 + 8) * 128 * 4);
    float* hB = (float*)alloc(((size_t)V2 + 8) * 128 * 4);
    unsigned short* FPhi = (unsigned short*)alloc((size_t)V2 * 128 * 2);
    unsigned short* FPlo = (unsigned short*)alloc((size_t)V2 * 128 * 2);
    float* vertsbuf = (float*)alloc((size_t)V2 * 3 * 4);
    float* Yc = (float*)alloc((size_t)V2 * 6 * 4);
    int* sampi = (int*)alloc((size_t)V2 * 12 * 4);
    float* sampw = (float*)alloc((size_t)V2 * 12 * 4);
    int* adj8 = (int*)alloc((size_t)V2 * 8 * 4);

    // ---- feature map transpose + hi/lo split ----
    transpose_hl<<<DIV_UP(256 * 56 * 56, 256), 256, 0, stream>>>(f3, ft0h, ft0l, 256, 56 * 56);
    transpose_hl<<<DIV_UP(512 * 28 * 28, 256), 256, 0, stream>>>(f4, ft1h, ft1l, 512, 28 * 28);
    transpose_hl<<<DIV_UP(512 * 14 * 14, 256), 256, 0, stream>>>(f5, ft2h, ft2l, 512, 14 * 14);

    // ---- single fused weight pack ----
    {
        PackArgs p;
        for (int s = 0; s < 3; ++s) {
            p.Win0[s] = (const float*)d_in[6 + s * 9 + 0];
            p.Win1[s] = (const float*)d_in[6 + s * 9 + 1];
            p.W0L[s] = (const float*)d_in[6 + s * 9 + 3];
            p.W1L[s] = (const float*)d_in[6 + s * 9 + 4];
            p.BtLp[s] = BtLp[s];
        }
        p.BtShi[0] = BtShi[0]; p.BtSlo[0] = BtSlo[0];
        p.BtShi[1] = BtShi[1]; p.BtSlo[1] = BtSlo[1];
        p.Bgh[0] = Bg0h; p.Bgl[0] = Bg0l;
        p.Bgh[1] = Bg1h; p.Bgl[1] = Bg1l;
        p.Bgh[2] = Bg2h; p.Bgl[2] = Bg2l;
        int total = 3 * 12 * 32768 + 2 * 256 * 128 + 768 * 256 + 2 * 768 * 512;
        pack_all<<<DIV_UP(total, 256), 256, 0, stream>>>(p);
    }

    // ---- G precompute (MFMA): G[s][pix][256] = ft_m @ W-slice ----
    {
        MArgs m = {};
        m.sstr = GS;
        m.Ahi = ft0h; m.Alo = ft0l; m.lda = 256;
        m.Bhi = Bg0h; m.Blo = Bg0l; m.K = 256;
        m.Y = Gbuf; m.V = 3136;
        dim3 g0(6, DIV_UP(3136, 64));
        mgemm<2><<<g0, 256, 0, stream>>>(m);
        m.Ahi = ft1h; m.Alo = ft1l; m.lda = 512;
        m.Bhi = Bg1h; m.Blo = Bg1l; m.K = 512;
        m.Y = Gbuf + (size_t)3136 * 256; m.V = 784;
        dim3 g1(6, DIV_UP(784, 64));
        mgemm<2><<<g1, 256, 0, stream>>>(m);
        m.Ahi = ft2h; m.Alo = ft2l; m.lda = 512;
        m.Bhi = Bg2h; m.Blo = Bg2l; m.K = 512;
        m.Y = Gbuf + (size_t)3920 * 256; m.V = 196;
        dim3 g2(6, DIV_UP(196, 64));
        mgemm<2><<<g2, 256, 0, stream>>>(m);
    }

    for (int si = 0; si < 3; ++si) {
        const float* Win0 = (const float*)d_in[6 + si * 9 + 0];
        const float* Win1 = (const float*)d_in[6 + si * 9 + 1];
        const float* bin = (const float*)d_in[6 + si * 9 + 2];
        const float* bs = (const float*)d_in[6 + si * 9 + 5];
        const float* Wc0 = (const float*)d_in[6 + si * 9 + 6];
        const float* Wc1 = (const float*)d_in[6 + si * 9 + 7];
        const float* bc = (const float*)d_in[6 + si * 9 + 8];
        const int* edges = (const int*)d_in[33 + si];
        int Ecur = E[si];
        const int* esrc = edges;
        const int* edst = edges + Ecur;
        int V = Vs[si];
        const float* vertsin = (si == 0) ? verts0 : vertsbuf;

        desc_adj_kernel<<<DIV_UP(V, 256), 256, 0, stream>>>(vertsin, cam_c, cam_f, imgsz, V,
                                                            esrc, edst, Ecur, sampi, sampw, adj8);
        // zero the pad row (index V) of both h buffers
        zero_pad<<<1, 128, 0, stream>>>(hA + (size_t)V * 128, hB + (size_t)V * 128);
        // shape GEMM first (pure store), then gather adds perceptual part
        if (si > 0) {
            MArgs m = {};
            m.Ahi = FPhi; m.Alo = FPlo; m.lda = 128;
            m.Bhi = BtShi[si - 1]; m.Blo = BtSlo[si - 1]; m.K = 128;
            m.Y = Ybuf; m.V = V;
            dim3 grid(2, DIV_UP(V, 64));
            mgemm<3><<<grid, 256, 0, stream>>>(m);
        }
        gather_kernel<<<DIV_UP(V, 4), 256, 0, stream>>>(Gbuf, GS, sampi, sampw, Ybuf, V, si,
                                                        Win0, Win1, (si == 0) ? verts0 : nullptr);
        combine_in<<<DIV_UP(V, 8), 256, 0, stream>>>(Ybuf, bin, adj8, hA, V);

        float* hcur = hA;
        float* hnext = hB;
        for (int ll = 0; ll < 12; ++ll) {
            LArgs a = {};
            a.h = hcur;
            a.Bp = BtLp[si] + (size_t)ll * 65536;
            a.adj8 = adj8;
            a.bias = bs + (size_t)ll * 128;
            a.hnext = hnext;
            a.V = V;
            lay_kernel<<<DIV_UP(V, 16), 256, 0, stream>>>(a);
            float* t = hcur; hcur = hnext; hnext = t;
        }

        coordgemm_kernel<<<DIV_UP(V * 6, 256), 256, 0, stream>>>(hcur, Wc0, Wc1, V, Yc);
        float* ctarget = (si == 2) ? (float*)d_out : vertsbuf;
        coordcombine_kernel<<<DIV_UP(V * 3, 256), 256, 0, stream>>>(Yc, bc, adj8, V, ctarget);
        if (si < 2) {
            const int* mid = (const int*)d_in[36 + si];
            int Nm = (si == 0) ? Nm0 : Nm1;
            unpool_kernel<<<V + Nm, 128, 0, stream>>>(vertsbuf, hcur, mid, V, Nm, FPhi, FPlo);
        }
    }
}